// Round 1
// baseline (168.896 us; speedup 1.0000x reference)
//
#include <hip/hip_runtime.h>

#define S_CAMS 4
#define D_BINS 32
#define CFEAT  96
#define HFD    45
#define WFD    80
#define PIX    (HFD*WFD)        // 3600
#define CHW    (128*PIX)        // per-camera input stride (128 channels)
#define YD     128
#define ZD     8
#define XD     128
#define NPTS   (YD*ZD*XD)       // 131072
#define CPC    24               // channels per chunk
#define NCHUNK 4                // 4*24 = 96

// Prep: (a) pix_T_ref = K @ E per camera (64 values), (b) softmax over the 32
// depth-logit channels per pixel -> depth volume in ws.
__global__ void prep_kernel(const float* __restrict__ feat,
                            const float* __restrict__ K,
                            const float* __restrict__ E,
                            float* __restrict__ mats,
                            float* __restrict__ depth) {
    int tid = blockIdx.x * blockDim.x + threadIdx.x;
    if (tid < S_CAMS * 16) {
        int s = tid >> 4, ij = tid & 15;
        int i = ij >> 2, j = ij & 3;
        const float* Ks = K + s * 16;
        const float* Es = E + s * 16;
        float acc = 0.f;
        #pragma unroll
        for (int k = 0; k < 4; ++k) acc += Ks[i*4+k] * Es[k*4+j];
        mats[tid] = acc;
    }
    if (tid < S_CAMS * PIX) {
        int s = tid / PIX;
        int p = tid - s * PIX;
        const float* base = feat + s * CHW + p;   // channels 0..31 are depth logits
        float v[D_BINS];
        float m = -3.4e38f;
        #pragma unroll
        for (int d = 0; d < D_BINS; ++d) {
            v[d] = base[d * PIX];
            m = fmaxf(m, v[d]);
        }
        float sum = 0.f;
        #pragma unroll
        for (int d = 0; d < D_BINS; ++d) {
            v[d] = __expf(v[d] - m);
            sum += v[d];
        }
        float inv = 1.f / sum;
        float* dst = depth + s * (D_BINS * PIX) + p;
        #pragma unroll
        for (int d = 0; d < D_BINS; ++d) dst[d * PIX] = v[d] * inv;
    }
}

// Main: one thread per voxel (y,z,x). Precompute 16 (weight, offset) pairs
// (4 cams x 4 spatial corners; depth-interp + valid + one_s + 1/denom all
// folded into the weight), then loop over a chunk of 24 channels doing
// 16 gathers + 16 FMAs each, writing out[((c*Z+z)*Y+y)*X+x].
__global__ __launch_bounds__(256) void lift_kernel(
    const float* __restrict__ feat,
    const float* __restrict__ E,
    const float* __restrict__ mats,
    const float* __restrict__ depth,
    float* __restrict__ out) {
    int tid = blockIdx.x * 256 + threadIdx.x;
    int xi = tid & (XD - 1);
    int zi = (tid >> 7) & (ZD - 1);
    int yi = tid >> 10;

    float xw = -25.f + (xi + 0.5f) * (50.f / XD);
    float yw = -25.f + (yi + 0.5f) * (50.f / YD);
    float zw = (zi + 0.5f) * 0.5f;

    float w[16];
    int   off[16];
    float one_sum = 0.f;

    #pragma unroll
    for (int s = 0; s < S_CAMS; ++s) {
        const float* P  = mats + s * 16;
        const float* Es = E + s * 16;
        float zcam = Es[8]*xw + Es[9]*yw + Es[10]*zw + Es[11];
        float px = P[0]*xw + P[1]*yw + P[2]*zw  + P[3];
        float py = P[4]*xw + P[5]*yw + P[6]*zw  + P[7];
        float pz = P[8]*xw + P[9]*yw + P[10]*zw + P[11];
        float zc = fmaxf(pz, 1e-6f);
        float xp = px / zc;
        float yp = py / zc;
        float zt = (float)(D_BINS - 1) * (zcam - 2.f) * (1.f / 30.f);
        float vmask = (xp > -0.5f && xp < (float)WFD - 0.5f &&
                       yp > -0.5f && yp < (float)HFD - 0.5f &&
                       zcam > 0.f) ? 1.f : 0.f;
        // grid_sample-style renormalization
        float us = xp * ((float)WFD / (WFD - 1)) - 0.5f;
        float vs = yp * ((float)HFD / (HFD - 1)) - 0.5f;
        float ts = zt * ((float)D_BINS / (D_BINS - 1)) - 0.5f;
        float u0f = floorf(us), v0f = floorf(vs), t0f = floorf(ts);
        float fu = us - u0f, fv = vs - v0f, ft = ts - t0f;
        int u0 = (int)u0f, v0 = (int)v0f, t0 = (int)t0f;
        int u1 = u0 + 1, v1 = v0 + 1, t1 = t0 + 1;
        float wu0 = 1.f - fu, wu1 = fu;
        float wv0 = 1.f - fv, wv1 = fv;
        float wz0 = (t0 >= 0 && t0 < D_BINS) ? (1.f - ft) : 0.f;
        float wz1 = (t1 >= 0 && t1 < D_BINS) ? ft : 0.f;
        float mu0 = (u0 >= 0 && u0 < WFD) ? 1.f : 0.f;
        float mu1 = (u1 >= 0 && u1 < WFD) ? 1.f : 0.f;
        float mv0 = (v0 >= 0 && v0 < HFD) ? 1.f : 0.f;
        float mv1 = (v1 >= 0 && v1 < HFD) ? 1.f : 0.f;
        int u0c = min(max(u0, 0), WFD - 1), u1c = min(max(u1, 0), WFD - 1);
        int v0c = min(max(v0, 0), HFD - 1), v1c = min(max(v1, 0), HFD - 1);
        int t0c = min(max(t0, 0), D_BINS - 1), t1c = min(max(t1, 0), D_BINS - 1);
        int p00 = v0c * WFD + u0c, p01 = v0c * WFD + u1c;
        int p10 = v1c * WFD + u0c, p11 = v1c * WFD + u1c;
        const float* dep0 = depth + s * (D_BINS * PIX) + t0c * PIX;
        const float* dep1 = depth + s * (D_BINS * PIX) + t1c * PIX;
        float g00 = wz0 * dep0[p00] + wz1 * dep1[p00];
        float g01 = wz0 * dep0[p01] + wz1 * dep1[p01];
        float g10 = wz0 * dep0[p10] + wz1 * dep1[p10];
        float g11 = wz0 * dep0[p11] + wz1 * dep1[p11];
        float m00 = mv0 * mu0, m01 = mv0 * mu1, m10 = mv1 * mu0, m11 = mv1 * mu1;
        float ws00 = wv0 * wu0 * m00, ws01 = wv0 * wu1 * m01;
        float ws10 = wv1 * wu0 * m10, ws11 = wv1 * wu1 * m11;
        float wsum_hw = ws00 + ws01 + ws10 + ws11;
        // one_mems: trilinear(ones)*valid then clip(.,1,None) -> max(.,1)
        float one_s = fmaxf(vmask * (wz0 + wz1) * wsum_hw, 1.f);
        one_sum += one_s;
        float sc = vmask * one_s;
        w[s*4+0] = sc * ws00 * g00;
        w[s*4+1] = sc * ws01 * g01;
        w[s*4+2] = sc * ws10 * g10;
        w[s*4+3] = sc * ws11 * g11;
        int base = s * CHW;
        off[s*4+0] = base + p00;
        off[s*4+1] = base + p01;
        off[s*4+2] = base + p10;
        off[s*4+3] = base + p11;
    }

    float inv = 1.f / (1e-6f + one_sum);
    #pragma unroll
    for (int k = 0; k < 16; ++k) w[k] *= inv;

    int c0 = blockIdx.y * CPC;
    int outsp = yi * XD + xi;
    for (int c = c0; c < c0 + CPC; ++c) {
        const float* fp = feat + (D_BINS + c) * PIX;  // feat channel c = input channel 32+c
        float acc = 0.f;
        #pragma unroll
        for (int k = 0; k < 16; ++k) acc = fmaf(w[k], fp[off[k]], acc);
        out[(c * ZD + zi) * (YD * XD) + outsp] = acc;
    }
}

extern "C" void kernel_launch(void* const* d_in, const int* in_sizes, int n_in,
                              void* d_out, int out_size, void* d_ws, size_t ws_size,
                              hipStream_t stream) {
    const float* feat = (const float*)d_in[0];   // (4,128,45,80) f32
    const float* K    = (const float*)d_in[1];   // (4,4,4) f32
    const float* E    = (const float*)d_in[2];   // (4,4,4) f32
    float* out  = (float*)d_out;                 // (1,768,128,128) f32
    float* mats  = (float*)d_ws;                 // 64 floats: pix_T_ref
    float* depth = mats + 64;                    // 4*32*45*80 floats softmax depth

    int prep_threads = S_CAMS * PIX;             // 14400 (>= 64 matrix threads)
    prep_kernel<<<dim3((prep_threads + 255) / 256), dim3(256), 0, stream>>>(
        feat, K, E, mats, depth);
    lift_kernel<<<dim3(NPTS / 256, NCHUNK), dim3(256), 0, stream>>>(
        feat, E, mats, depth, out);
}

// Round 3
// 149.047 us; speedup vs baseline: 1.1332x; 1.1332x over previous
//
#include <hip/hip_runtime.h>

#define S_CAMS 4
#define D_BINS 32
#define CFEAT  96
#define HFD    45
#define WFD    80
#define PIX    (HFD*WFD)        // 3600
#define CHW    (128*PIX)        // per-camera input stride (128 channels)
#define YD     128
#define ZD     8
#define XD     128
#define NPTS   (YD*ZD*XD)       // 131072
#define CPC    24               // channels per chunk
#define NCHUNK 4                // 4*24 = 96

#define NB_SOFT 57              // ceil(4*3600/256) softmax blocks
#define NB_TR   1350            // 4*24*3600/256 transpose blocks

// ---------------- FAST PATH (needs ~7.4 MB ws) ----------------
// Fused prep: blocks [0,NB_SOFT): mats = K@E + per-pixel softmax over 32
// depth logits -> depthT[s][pix][32] (channel-contiguous).
// blocks [NB_SOFT, NB_SOFT+NB_TR): transpose feat channels ->
// featT[s][pix][96]; reads coalesced over pix, float4 writes.
__global__ void prep_fast(const float* __restrict__ feat,
                          const float* __restrict__ K,
                          const float* __restrict__ E,
                          float* __restrict__ mats,
                          float* __restrict__ depthT,
                          float* __restrict__ featT) {
    int b = blockIdx.x;
    if (b < NB_SOFT) {
        int tid = b * 256 + threadIdx.x;
        if (tid < S_CAMS * 16) {
            int s = tid >> 4, ij = tid & 15;
            int i = ij >> 2, j = ij & 3;
            const float* Ks = K + s * 16;
            const float* Es = E + s * 16;
            float acc = 0.f;
            #pragma unroll
            for (int k = 0; k < 4; ++k) acc += Ks[i*4+k] * Es[k*4+j];
            mats[tid] = acc;
        }
        if (tid < S_CAMS * PIX) {
            int s = tid / PIX;
            int p = tid - s * PIX;
            const float* base = feat + s * CHW + p;   // ch 0..31 = depth logits
            float v[D_BINS];
            float m = -3.4e38f;
            #pragma unroll
            for (int d = 0; d < D_BINS; ++d) {
                v[d] = base[d * PIX];
                m = fmaxf(m, v[d]);
            }
            float sum = 0.f;
            #pragma unroll
            for (int d = 0; d < D_BINS; ++d) {
                v[d] = __expf(v[d] - m);
                sum += v[d];
            }
            float inv = 1.f / sum;
            float4* dst = (float4*)(depthT + (size_t)tid * D_BINS);
            #pragma unroll
            for (int d = 0; d < D_BINS; d += 4)
                dst[d >> 2] = make_float4(v[d]*inv, v[d+1]*inv, v[d+2]*inv, v[d+3]*inv);
        }
    } else {
        int t = (b - NB_SOFT) * 256 + threadIdx.x;   // < 4*24*3600
        int s  = t / (24 * PIX);
        int r  = t - s * (24 * PIX);
        int c4 = r / PIX;
        int p  = r - c4 * PIX;
        const float* src = feat + s * CHW + (D_BINS + c4 * 4) * PIX + p;
        float4 v = make_float4(src[0], src[PIX], src[2*PIX], src[3*PIX]);
        *(float4*)(featT + (size_t)(s * PIX + p) * CFEAT + c4 * 4) = v;
    }
}

// Main (fast): one thread per voxel. 16 (weight, offset) pairs (4 cams x 4
// spatial corners; depth-interp + valid + one_s + 1/denom folded into the
// weight), then per 24-channel chunk: 16 corners x 6 float4 contiguous loads.
__global__ __launch_bounds__(256, 4) void lift_fast(
    const float* __restrict__ featT,
    const float* __restrict__ E,
    const float* __restrict__ mats,
    const float* __restrict__ depthT,
    float* __restrict__ out) {
    int tid = blockIdx.x * 256 + threadIdx.x;
    int xi = tid & (XD - 1);
    int zi = (tid >> 7) & (ZD - 1);
    int yi = tid >> 10;

    float xw = -25.f + (xi + 0.5f) * (50.f / XD);
    float yw = -25.f + (yi + 0.5f) * (50.f / YD);
    float zw = (zi + 0.5f) * 0.5f;

    float w[16];
    int   off[16];
    float one_sum = 0.f;

    #pragma unroll
    for (int s = 0; s < S_CAMS; ++s) {
        const float* P  = mats + s * 16;
        const float* Es = E + s * 16;
        float zcam = Es[8]*xw + Es[9]*yw + Es[10]*zw + Es[11];
        float px = P[0]*xw + P[1]*yw + P[2]*zw  + P[3];
        float py = P[4]*xw + P[5]*yw + P[6]*zw  + P[7];
        float pz = P[8]*xw + P[9]*yw + P[10]*zw + P[11];
        float zc = fmaxf(pz, 1e-6f);
        float xp = px / zc;
        float yp = py / zc;
        float zt = (float)(D_BINS - 1) * (zcam - 2.f) * (1.f / 30.f);
        float vmask = (xp > -0.5f && xp < (float)WFD - 0.5f &&
                       yp > -0.5f && yp < (float)HFD - 0.5f &&
                       zcam > 0.f) ? 1.f : 0.f;
        float us = xp * ((float)WFD / (WFD - 1)) - 0.5f;
        float vs = yp * ((float)HFD / (HFD - 1)) - 0.5f;
        float ts = zt * ((float)D_BINS / (D_BINS - 1)) - 0.5f;
        float u0f = floorf(us), v0f = floorf(vs), t0f = floorf(ts);
        float fu = us - u0f, fv = vs - v0f, ft = ts - t0f;
        int u0 = (int)u0f, v0 = (int)v0f, t0 = (int)t0f;
        int u1 = u0 + 1, v1 = v0 + 1, t1 = t0 + 1;
        float wu0 = 1.f - fu, wu1 = fu;
        float wv0 = 1.f - fv, wv1 = fv;
        float wz0 = (t0 >= 0 && t0 < D_BINS) ? (1.f - ft) : 0.f;
        float wz1 = (t1 >= 0 && t1 < D_BINS) ? ft : 0.f;
        float mu0 = (u0 >= 0 && u0 < WFD) ? 1.f : 0.f;
        float mu1 = (u1 >= 0 && u1 < WFD) ? 1.f : 0.f;
        float mv0 = (v0 >= 0 && v0 < HFD) ? 1.f : 0.f;
        float mv1 = (v1 >= 0 && v1 < HFD) ? 1.f : 0.f;
        int u0c = min(max(u0, 0), WFD - 1), u1c = min(max(u1, 0), WFD - 1);
        int v0c = min(max(v0, 0), HFD - 1), v1c = min(max(v1, 0), HFD - 1);
        int t0c = min(max(t0, 0), D_BINS - 1), t1c = min(max(t1, 0), D_BINS - 1);
        int p00 = v0c * WFD + u0c, p01 = v0c * WFD + u1c;
        int p10 = v1c * WFD + u0c, p11 = v1c * WFD + u1c;
        const float* dT = depthT + (size_t)(s * PIX) * D_BINS;
        const float* d00 = dT + p00 * D_BINS;
        const float* d01 = dT + p01 * D_BINS;
        const float* d10 = dT + p10 * D_BINS;
        const float* d11 = dT + p11 * D_BINS;
        float g00 = wz0 * d00[t0c] + wz1 * d00[t1c];
        float g01 = wz0 * d01[t0c] + wz1 * d01[t1c];
        float g10 = wz0 * d10[t0c] + wz1 * d10[t1c];
        float g11 = wz0 * d11[t0c] + wz1 * d11[t1c];
        float m00 = mv0 * mu0, m01 = mv0 * mu1, m10 = mv1 * mu0, m11 = mv1 * mu1;
        float ws00 = wv0 * wu0 * m00, ws01 = wv0 * wu1 * m01;
        float ws10 = wv1 * wu0 * m10, ws11 = wv1 * wu1 * m11;
        float wsum_hw = ws00 + ws01 + ws10 + ws11;
        float one_s = fmaxf(vmask * (wz0 + wz1) * wsum_hw, 1.f);
        one_sum += one_s;
        float sc = vmask * one_s;
        w[s*4+0] = sc * ws00 * g00;
        w[s*4+1] = sc * ws01 * g01;
        w[s*4+2] = sc * ws10 * g10;
        w[s*4+3] = sc * ws11 * g11;
        off[s*4+0] = (s * PIX + p00) * CFEAT;
        off[s*4+1] = (s * PIX + p01) * CFEAT;
        off[s*4+2] = (s * PIX + p10) * CFEAT;
        off[s*4+3] = (s * PIX + p11) * CFEAT;
    }

    float inv = 1.f / (1e-6f + one_sum);
    #pragma unroll
    for (int k = 0; k < 16; ++k) w[k] *= inv;

    int c0 = blockIdx.y * CPC;
    float acc[CPC];
    #pragma unroll
    for (int j = 0; j < CPC; ++j) acc[j] = 0.f;

    #pragma unroll 2
    for (int k = 0; k < 16; ++k) {
        const float4* fp = (const float4*)(featT + off[k] + c0);
        float wk = w[k];
        #pragma unroll
        for (int j = 0; j < CPC / 4; ++j) {
            float4 v = fp[j];
            acc[4*j+0] = fmaf(wk, v.x, acc[4*j+0]);
            acc[4*j+1] = fmaf(wk, v.y, acc[4*j+1]);
            acc[4*j+2] = fmaf(wk, v.z, acc[4*j+2]);
            acc[4*j+3] = fmaf(wk, v.w, acc[4*j+3]);
        }
    }

    int outsp = yi * XD + xi;
    #pragma unroll
    for (int j = 0; j < CPC; ++j) {
        int c = c0 + j;
        out[(c * ZD + zi) * (YD * XD) + outsp] = acc[j];
    }
}

// ---------------- FALLBACK PATH (R1, proven, ~1.84 MB ws) ----------------
__global__ void prep_fb(const float* __restrict__ feat,
                        const float* __restrict__ K,
                        const float* __restrict__ E,
                        float* __restrict__ mats,
                        float* __restrict__ depth) {
    int tid = blockIdx.x * blockDim.x + threadIdx.x;
    if (tid < S_CAMS * 16) {
        int s = tid >> 4, ij = tid & 15;
        int i = ij >> 2, j = ij & 3;
        const float* Ks = K + s * 16;
        const float* Es = E + s * 16;
        float acc = 0.f;
        #pragma unroll
        for (int k = 0; k < 4; ++k) acc += Ks[i*4+k] * Es[k*4+j];
        mats[tid] = acc;
    }
    if (tid < S_CAMS * PIX) {
        int s = tid / PIX;
        int p = tid - s * PIX;
        const float* base = feat + s * CHW + p;
        float v[D_BINS];
        float m = -3.4e38f;
        #pragma unroll
        for (int d = 0; d < D_BINS; ++d) {
            v[d] = base[d * PIX];
            m = fmaxf(m, v[d]);
        }
        float sum = 0.f;
        #pragma unroll
        for (int d = 0; d < D_BINS; ++d) {
            v[d] = __expf(v[d] - m);
            sum += v[d];
        }
        float inv = 1.f / sum;
        float* dst = depth + s * (D_BINS * PIX) + p;
        #pragma unroll
        for (int d = 0; d < D_BINS; ++d) dst[d * PIX] = v[d] * inv;
    }
}

__global__ __launch_bounds__(256) void lift_fb(
    const float* __restrict__ feat,
    const float* __restrict__ E,
    const float* __restrict__ mats,
    const float* __restrict__ depth,
    float* __restrict__ out) {
    int tid = blockIdx.x * 256 + threadIdx.x;
    int xi = tid & (XD - 1);
    int zi = (tid >> 7) & (ZD - 1);
    int yi = tid >> 10;

    float xw = -25.f + (xi + 0.5f) * (50.f / XD);
    float yw = -25.f + (yi + 0.5f) * (50.f / YD);
    float zw = (zi + 0.5f) * 0.5f;

    float w[16];
    int   off[16];
    float one_sum = 0.f;

    #pragma unroll
    for (int s = 0; s < S_CAMS; ++s) {
        const float* P  = mats + s * 16;
        const float* Es = E + s * 16;
        float zcam = Es[8]*xw + Es[9]*yw + Es[10]*zw + Es[11];
        float px = P[0]*xw + P[1]*yw + P[2]*zw  + P[3];
        float py = P[4]*xw + P[5]*yw + P[6]*zw  + P[7];
        float pz = P[8]*xw + P[9]*yw + P[10]*zw + P[11];
        float zc = fmaxf(pz, 1e-6f);
        float xp = px / zc;
        float yp = py / zc;
        float zt = (float)(D_BINS - 1) * (zcam - 2.f) * (1.f / 30.f);
        float vmask = (xp > -0.5f && xp < (float)WFD - 0.5f &&
                       yp > -0.5f && yp < (float)HFD - 0.5f &&
                       zcam > 0.f) ? 1.f : 0.f;
        float us = xp * ((float)WFD / (WFD - 1)) - 0.5f;
        float vs = yp * ((float)HFD / (HFD - 1)) - 0.5f;
        float ts = zt * ((float)D_BINS / (D_BINS - 1)) - 0.5f;
        float u0f = floorf(us), v0f = floorf(vs), t0f = floorf(ts);
        float fu = us - u0f, fv = vs - v0f, ft = ts - t0f;
        int u0 = (int)u0f, v0 = (int)v0f, t0 = (int)t0f;
        int u1 = u0 + 1, v1 = v0 + 1, t1 = t0 + 1;
        float wu0 = 1.f - fu, wu1 = fu;
        float wv0 = 1.f - fv, wv1 = fv;
        float wz0 = (t0 >= 0 && t0 < D_BINS) ? (1.f - ft) : 0.f;
        float wz1 = (t1 >= 0 && t1 < D_BINS) ? ft : 0.f;
        float mu0 = (u0 >= 0 && u0 < WFD) ? 1.f : 0.f;
        float mu1 = (u1 >= 0 && u1 < WFD) ? 1.f : 0.f;
        float mv0 = (v0 >= 0 && v0 < HFD) ? 1.f : 0.f;
        float mv1 = (v1 >= 0 && v1 < HFD) ? 1.f : 0.f;
        int u0c = min(max(u0, 0), WFD - 1), u1c = min(max(u1, 0), WFD - 1);
        int v0c = min(max(v0, 0), HFD - 1), v1c = min(max(v1, 0), HFD - 1);
        int t0c = min(max(t0, 0), D_BINS - 1), t1c = min(max(t1, 0), D_BINS - 1);
        int p00 = v0c * WFD + u0c, p01 = v0c * WFD + u1c;
        int p10 = v1c * WFD + u0c, p11 = v1c * WFD + u1c;
        const float* dep0 = depth + s * (D_BINS * PIX) + t0c * PIX;
        const float* dep1 = depth + s * (D_BINS * PIX) + t1c * PIX;
        float g00 = wz0 * dep0[p00] + wz1 * dep1[p00];
        float g01 = wz0 * dep0[p01] + wz1 * dep1[p01];
        float g10 = wz0 * dep0[p10] + wz1 * dep1[p10];
        float g11 = wz0 * dep0[p11] + wz1 * dep1[p11];
        float m00 = mv0 * mu0, m01 = mv0 * mu1, m10 = mv1 * mu0, m11 = mv1 * mu1;
        float ws00 = wv0 * wu0 * m00, ws01 = wv0 * wu1 * m01;
        float ws10 = wv1 * wu0 * m10, ws11 = wv1 * wu1 * m11;
        float wsum_hw = ws00 + ws01 + ws10 + ws11;
        float one_s = fmaxf(vmask * (wz0 + wz1) * wsum_hw, 1.f);
        one_sum += one_s;
        float sc = vmask * one_s;
        w[s*4+0] = sc * ws00 * g00;
        w[s*4+1] = sc * ws01 * g01;
        w[s*4+2] = sc * ws10 * g10;
        w[s*4+3] = sc * ws11 * g11;
        int base = s * CHW;
        off[s*4+0] = base + p00;
        off[s*4+1] = base + p01;
        off[s*4+2] = base + p10;
        off[s*4+3] = base + p11;
    }

    float inv = 1.f / (1e-6f + one_sum);
    #pragma unroll
    for (int k = 0; k < 16; ++k) w[k] *= inv;

    int c0 = blockIdx.y * CPC;
    int outsp = yi * XD + xi;
    for (int c = c0; c < c0 + CPC; ++c) {
        const float* fp = feat + (D_BINS + c) * PIX;
        float acc = 0.f;
        #pragma unroll
        for (int k = 0; k < 16; ++k) acc = fmaf(w[k], fp[off[k]], acc);
        out[(c * ZD + zi) * (YD * XD) + outsp] = acc;
    }
}

extern "C" void kernel_launch(void* const* d_in, const int* in_sizes, int n_in,
                              void* d_out, int out_size, void* d_ws, size_t ws_size,
                              hipStream_t stream) {
    const float* feat = (const float*)d_in[0];   // (4,128,45,80) f32
    const float* K    = (const float*)d_in[1];   // (4,4,4) f32
    const float* E    = (const float*)d_in[2];   // (4,4,4) f32
    float* out  = (float*)d_out;                 // (1,768,128,128) f32

    const size_t n_depth = (size_t)S_CAMS * PIX * D_BINS;   // 460800
    const size_t n_feat  = (size_t)S_CAMS * PIX * CFEAT;    // 1382400
    const size_t need_fast = (64 + n_depth + n_feat) * sizeof(float);  // ~7.4 MB

    float* mats   = (float*)d_ws;
    float* depthT = mats + 64;

    if (ws_size >= need_fast) {
        float* featT = depthT + n_depth;
        prep_fast<<<dim3(NB_SOFT + NB_TR), dim3(256), 0, stream>>>(
            feat, K, E, mats, depthT, featT);
        lift_fast<<<dim3(NPTS / 256, NCHUNK), dim3(256), 0, stream>>>(
            featT, E, mats, depthT, out);
    } else {
        // proven R1 path: depth in [s][d][pix] layout, gather from original feat
        prep_fb<<<dim3((S_CAMS * PIX + 255) / 256), dim3(256), 0, stream>>>(
            feat, K, E, mats, depthT);
        lift_fb<<<dim3(NPTS / 256, NCHUNK), dim3(256), 0, stream>>>(
            feat, E, mats, depthT, out);
    }
}

// Round 4
// 127.823 us; speedup vs baseline: 1.3213x; 1.1660x over previous
//
#include <hip/hip_runtime.h>

#define S_CAMS 4
#define D_BINS 32
#define CFEAT  96
#define HFD    45
#define WFD    80
#define PIX    (HFD*WFD)        // 3600
#define CHW    (128*PIX)        // per-camera input stride (128 channels)
#define YD     128
#define ZD     8
#define XD     128
#define NPTS   (YD*ZD*XD)       // 131072
#define CPC    24               // channels per chunk
#define NCHUNK 4                // 4*24 = 96

#define NB_SOFT 57              // ceil(4*3600/256) softmax blocks
#define NB_TR   675             // 4*12*3600/256 fp16-transpose blocks

typedef _Float16 h8 __attribute__((ext_vector_type(8)));   // 16 B

// ---------------- FAST PATH (~4.6 MB ws) ----------------
// Fused prep: blocks [0,NB_SOFT): mats = K@E + per-pixel softmax over 32
// depth logits -> depthT[s][pix][32] f32 (channel-contiguous).
// blocks [NB_SOFT,NB_SOFT+NB_TR): transpose+cast feat channels ->
// featT[s][pix][96] fp16; reads coalesced over pix, 16B h8 writes.
__global__ void prep_fast(const float* __restrict__ feat,
                          const float* __restrict__ K,
                          const float* __restrict__ E,
                          float* __restrict__ mats,
                          float* __restrict__ depthT,
                          _Float16* __restrict__ featT) {
    int b = blockIdx.x;
    if (b < NB_SOFT) {
        int tid = b * 256 + threadIdx.x;
        if (tid < S_CAMS * 16) {
            int s = tid >> 4, ij = tid & 15;
            int i = ij >> 2, j = ij & 3;
            const float* Ks = K + s * 16;
            const float* Es = E + s * 16;
            float acc = 0.f;
            #pragma unroll
            for (int k = 0; k < 4; ++k) acc += Ks[i*4+k] * Es[k*4+j];
            mats[tid] = acc;
        }
        if (tid < S_CAMS * PIX) {
            int s = tid / PIX;
            int p = tid - s * PIX;
            const float* base = feat + s * CHW + p;   // ch 0..31 = depth logits
            float v[D_BINS];
            float m = -3.4e38f;
            #pragma unroll
            for (int d = 0; d < D_BINS; ++d) {
                v[d] = base[d * PIX];
                m = fmaxf(m, v[d]);
            }
            float sum = 0.f;
            #pragma unroll
            for (int d = 0; d < D_BINS; ++d) {
                v[d] = __expf(v[d] - m);
                sum += v[d];
            }
            float inv = 1.f / sum;
            float4* dst = (float4*)(depthT + (size_t)tid * D_BINS);
            #pragma unroll
            for (int d = 0; d < D_BINS; d += 4)
                dst[d >> 2] = make_float4(v[d]*inv, v[d+1]*inv, v[d+2]*inv, v[d+3]*inv);
        }
    } else {
        int t = (b - NB_SOFT) * 256 + threadIdx.x;   // < 4*12*3600 exactly
        int s  = t / (12 * PIX);
        int r  = t - s * (12 * PIX);
        int c8 = r / PIX;
        int p  = r - c8 * PIX;
        const float* src = feat + s * CHW + (D_BINS + c8 * 8) * PIX + p;
        h8 o;
        #pragma unroll
        for (int i = 0; i < 8; ++i) o[i] = (_Float16)src[i * PIX];
        ((h8*)featT)[(size_t)(s * PIX + p) * 12 + c8] = o;
    }
}

// Main (fast): one thread per voxel. 16 (weight, offset) pairs (4 cams x 4
// spatial corners; depth-interp + valid + one_s + 1/denom folded into the
// weight), then per 24-channel chunk: 16 corners x 3 h8 (fp16) loads.
__global__ __launch_bounds__(256, 4) void lift_fast(
    const _Float16* __restrict__ featT,
    const float* __restrict__ E,
    const float* __restrict__ mats,
    const float* __restrict__ depthT,
    float* __restrict__ out) {
    int tid = blockIdx.x * 256 + threadIdx.x;
    int xi = tid & (XD - 1);
    int zi = (tid >> 7) & (ZD - 1);
    int yi = tid >> 10;

    float xw = -25.f + (xi + 0.5f) * (50.f / XD);
    float yw = -25.f + (yi + 0.5f) * (50.f / YD);
    float zw = (zi + 0.5f) * 0.5f;

    float w[16];
    int   off[16];
    float one_sum = 0.f;

    #pragma unroll
    for (int s = 0; s < S_CAMS; ++s) {
        const float* P  = mats + s * 16;
        const float* Es = E + s * 16;
        float zcam = Es[8]*xw + Es[9]*yw + Es[10]*zw + Es[11];
        float px = P[0]*xw + P[1]*yw + P[2]*zw  + P[3];
        float py = P[4]*xw + P[5]*yw + P[6]*zw  + P[7];
        float pz = P[8]*xw + P[9]*yw + P[10]*zw + P[11];
        float zc = fmaxf(pz, 1e-6f);
        float xp = px / zc;
        float yp = py / zc;
        float zt = (float)(D_BINS - 1) * (zcam - 2.f) * (1.f / 30.f);
        float vmask = (xp > -0.5f && xp < (float)WFD - 0.5f &&
                       yp > -0.5f && yp < (float)HFD - 0.5f &&
                       zcam > 0.f) ? 1.f : 0.f;
        float us = xp * ((float)WFD / (WFD - 1)) - 0.5f;
        float vs = yp * ((float)HFD / (HFD - 1)) - 0.5f;
        float ts = zt * ((float)D_BINS / (D_BINS - 1)) - 0.5f;
        float u0f = floorf(us), v0f = floorf(vs), t0f = floorf(ts);
        float fu = us - u0f, fv = vs - v0f, ft = ts - t0f;
        int u0 = (int)u0f, v0 = (int)v0f, t0 = (int)t0f;
        int u1 = u0 + 1, v1 = v0 + 1, t1 = t0 + 1;
        float wu0 = 1.f - fu, wu1 = fu;
        float wv0 = 1.f - fv, wv1 = fv;
        float wz0 = (t0 >= 0 && t0 < D_BINS) ? (1.f - ft) : 0.f;
        float wz1 = (t1 >= 0 && t1 < D_BINS) ? ft : 0.f;
        float mu0 = (u0 >= 0 && u0 < WFD) ? 1.f : 0.f;
        float mu1 = (u1 >= 0 && u1 < WFD) ? 1.f : 0.f;
        float mv0 = (v0 >= 0 && v0 < HFD) ? 1.f : 0.f;
        float mv1 = (v1 >= 0 && v1 < HFD) ? 1.f : 0.f;
        int u0c = min(max(u0, 0), WFD - 1), u1c = min(max(u1, 0), WFD - 1);
        int v0c = min(max(v0, 0), HFD - 1), v1c = min(max(v1, 0), HFD - 1);
        int t0c = min(max(t0, 0), D_BINS - 1), t1c = min(max(t1, 0), D_BINS - 1);
        int p00 = v0c * WFD + u0c, p01 = v0c * WFD + u1c;
        int p10 = v1c * WFD + u0c, p11 = v1c * WFD + u1c;
        const float* dT = depthT + (size_t)(s * PIX) * D_BINS;
        const float* d00 = dT + p00 * D_BINS;
        const float* d01 = dT + p01 * D_BINS;
        const float* d10 = dT + p10 * D_BINS;
        const float* d11 = dT + p11 * D_BINS;
        float g00 = wz0 * d00[t0c] + wz1 * d00[t1c];
        float g01 = wz0 * d01[t0c] + wz1 * d01[t1c];
        float g10 = wz0 * d10[t0c] + wz1 * d10[t1c];
        float g11 = wz0 * d11[t0c] + wz1 * d11[t1c];
        float m00 = mv0 * mu0, m01 = mv0 * mu1, m10 = mv1 * mu0, m11 = mv1 * mu1;
        float ws00 = wv0 * wu0 * m00, ws01 = wv0 * wu1 * m01;
        float ws10 = wv1 * wu0 * m10, ws11 = wv1 * wu1 * m11;
        float wsum_hw = ws00 + ws01 + ws10 + ws11;
        float one_s = fmaxf(vmask * (wz0 + wz1) * wsum_hw, 1.f);
        one_sum += one_s;
        float sc = vmask * one_s;
        w[s*4+0] = sc * ws00 * g00;
        w[s*4+1] = sc * ws01 * g01;
        w[s*4+2] = sc * ws10 * g10;
        w[s*4+3] = sc * ws11 * g11;
        off[s*4+0] = (s * PIX + p00) * CFEAT;
        off[s*4+1] = (s * PIX + p01) * CFEAT;
        off[s*4+2] = (s * PIX + p10) * CFEAT;
        off[s*4+3] = (s * PIX + p11) * CFEAT;
    }

    float inv = 1.f / (1e-6f + one_sum);
    #pragma unroll
    for (int k = 0; k < 16; ++k) w[k] *= inv;

    int c0 = blockIdx.y * CPC;
    float acc[CPC];
    #pragma unroll
    for (int j = 0; j < CPC; ++j) acc[j] = 0.f;

    #pragma unroll 2
    for (int k = 0; k < 16; ++k) {
        const h8* fp = (const h8*)(featT + off[k] + c0);
        float wk = w[k];
        #pragma unroll
        for (int j = 0; j < CPC / 8; ++j) {
            h8 v = fp[j];
            #pragma unroll
            for (int i = 0; i < 8; ++i)
                acc[8*j+i] = fmaf(wk, (float)v[i], acc[8*j+i]);
        }
    }

    int outsp = yi * XD + xi;
    #pragma unroll
    for (int j = 0; j < CPC; ++j) {
        int c = c0 + j;
        __builtin_nontemporal_store(acc[j], &out[(c * ZD + zi) * (YD * XD) + outsp]);
    }
}

// ---------------- FALLBACK PATH (R1, proven, ~1.84 MB ws) ----------------
__global__ void prep_fb(const float* __restrict__ feat,
                        const float* __restrict__ K,
                        const float* __restrict__ E,
                        float* __restrict__ mats,
                        float* __restrict__ depth) {
    int tid = blockIdx.x * blockDim.x + threadIdx.x;
    if (tid < S_CAMS * 16) {
        int s = tid >> 4, ij = tid & 15;
        int i = ij >> 2, j = ij & 3;
        const float* Ks = K + s * 16;
        const float* Es = E + s * 16;
        float acc = 0.f;
        #pragma unroll
        for (int k = 0; k < 4; ++k) acc += Ks[i*4+k] * Es[k*4+j];
        mats[tid] = acc;
    }
    if (tid < S_CAMS * PIX) {
        int s = tid / PIX;
        int p = tid - s * PIX;
        const float* base = feat + s * CHW + p;
        float v[D_BINS];
        float m = -3.4e38f;
        #pragma unroll
        for (int d = 0; d < D_BINS; ++d) {
            v[d] = base[d * PIX];
            m = fmaxf(m, v[d]);
        }
        float sum = 0.f;
        #pragma unroll
        for (int d = 0; d < D_BINS; ++d) {
            v[d] = __expf(v[d] - m);
            sum += v[d];
        }
        float inv = 1.f / sum;
        float* dst = depth + s * (D_BINS * PIX) + p;
        #pragma unroll
        for (int d = 0; d < D_BINS; ++d) dst[d * PIX] = v[d] * inv;
    }
}

__global__ __launch_bounds__(256) void lift_fb(
    const float* __restrict__ feat,
    const float* __restrict__ E,
    const float* __restrict__ mats,
    const float* __restrict__ depth,
    float* __restrict__ out) {
    int tid = blockIdx.x * 256 + threadIdx.x;
    int xi = tid & (XD - 1);
    int zi = (tid >> 7) & (ZD - 1);
    int yi = tid >> 10;

    float xw = -25.f + (xi + 0.5f) * (50.f / XD);
    float yw = -25.f + (yi + 0.5f) * (50.f / YD);
    float zw = (zi + 0.5f) * 0.5f;

    float w[16];
    int   off[16];
    float one_sum = 0.f;

    #pragma unroll
    for (int s = 0; s < S_CAMS; ++s) {
        const float* P  = mats + s * 16;
        const float* Es = E + s * 16;
        float zcam = Es[8]*xw + Es[9]*yw + Es[10]*zw + Es[11];
        float px = P[0]*xw + P[1]*yw + P[2]*zw  + P[3];
        float py = P[4]*xw + P[5]*yw + P[6]*zw  + P[7];
        float pz = P[8]*xw + P[9]*yw + P[10]*zw + P[11];
        float zc = fmaxf(pz, 1e-6f);
        float xp = px / zc;
        float yp = py / zc;
        float zt = (float)(D_BINS - 1) * (zcam - 2.f) * (1.f / 30.f);
        float vmask = (xp > -0.5f && xp < (float)WFD - 0.5f &&
                       yp > -0.5f && yp < (float)HFD - 0.5f &&
                       zcam > 0.f) ? 1.f : 0.f;
        float us = xp * ((float)WFD / (WFD - 1)) - 0.5f;
        float vs = yp * ((float)HFD / (HFD - 1)) - 0.5f;
        float ts = zt * ((float)D_BINS / (D_BINS - 1)) - 0.5f;
        float u0f = floorf(us), v0f = floorf(vs), t0f = floorf(ts);
        float fu = us - u0f, fv = vs - v0f, ft = ts - t0f;
        int u0 = (int)u0f, v0 = (int)v0f, t0 = (int)t0f;
        int u1 = u0 + 1, v1 = v0 + 1, t1 = t0 + 1;
        float wu0 = 1.f - fu, wu1 = fu;
        float wv0 = 1.f - fv, wv1 = fv;
        float wz0 = (t0 >= 0 && t0 < D_BINS) ? (1.f - ft) : 0.f;
        float wz1 = (t1 >= 0 && t1 < D_BINS) ? ft : 0.f;
        float mu0 = (u0 >= 0 && u0 < WFD) ? 1.f : 0.f;
        float mu1 = (u1 >= 0 && u1 < WFD) ? 1.f : 0.f;
        float mv0 = (v0 >= 0 && v0 < HFD) ? 1.f : 0.f;
        float mv1 = (v1 >= 0 && v1 < HFD) ? 1.f : 0.f;
        int u0c = min(max(u0, 0), WFD - 1), u1c = min(max(u1, 0), WFD - 1);
        int v0c = min(max(v0, 0), HFD - 1), v1c = min(max(v1, 0), HFD - 1);
        int t0c = min(max(t0, 0), D_BINS - 1), t1c = min(max(t1, 0), D_BINS - 1);
        int p00 = v0c * WFD + u0c, p01 = v0c * WFD + u1c;
        int p10 = v1c * WFD + u0c, p11 = v1c * WFD + u1c;
        const float* dep0 = depth + s * (D_BINS * PIX) + t0c * PIX;
        const float* dep1 = depth + s * (D_BINS * PIX) + t1c * PIX;
        float g00 = wz0 * dep0[p00] + wz1 * dep1[p00];
        float g01 = wz0 * dep0[p01] + wz1 * dep1[p01];
        float g10 = wz0 * dep0[p10] + wz1 * dep1[p10];
        float g11 = wz0 * dep0[p11] + wz1 * dep1[p11];
        float m00 = mv0 * mu0, m01 = mv0 * mu1, m10 = mv1 * mu0, m11 = mv1 * mu1;
        float ws00 = wv0 * wu0 * m00, ws01 = wv0 * wu1 * m01;
        float ws10 = wv1 * wu0 * m10, ws11 = wv1 * wu1 * m11;
        float wsum_hw = ws00 + ws01 + ws10 + ws11;
        float one_s = fmaxf(vmask * (wz0 + wz1) * wsum_hw, 1.f);
        one_sum += one_s;
        float sc = vmask * one_s;
        w[s*4+0] = sc * ws00 * g00;
        w[s*4+1] = sc * ws01 * g01;
        w[s*4+2] = sc * ws10 * g10;
        w[s*4+3] = sc * ws11 * g11;
        int base = s * CHW;
        off[s*4+0] = base + p00;
        off[s*4+1] = base + p01;
        off[s*4+2] = base + p10;
        off[s*4+3] = base + p11;
    }

    float inv = 1.f / (1e-6f + one_sum);
    #pragma unroll
    for (int k = 0; k < 16; ++k) w[k] *= inv;

    int c0 = blockIdx.y * CPC;
    int outsp = yi * XD + xi;
    for (int c = c0; c < c0 + CPC; ++c) {
        const float* fp = feat + (D_BINS + c) * PIX;
        float acc = 0.f;
        #pragma unroll
        for (int k = 0; k < 16; ++k) acc = fmaf(w[k], fp[off[k]], acc);
        out[(c * ZD + zi) * (YD * XD) + outsp] = acc;
    }
}

extern "C" void kernel_launch(void* const* d_in, const int* in_sizes, int n_in,
                              void* d_out, int out_size, void* d_ws, size_t ws_size,
                              hipStream_t stream) {
    const float* feat = (const float*)d_in[0];   // (4,128,45,80) f32
    const float* K    = (const float*)d_in[1];   // (4,4,4) f32
    const float* E    = (const float*)d_in[2];   // (4,4,4) f32
    float* out  = (float*)d_out;                 // (1,768,128,128) f32

    const size_t n_depth = (size_t)S_CAMS * PIX * D_BINS;   // 460800 f32
    const size_t n_feat  = (size_t)S_CAMS * PIX * CFEAT;    // 1382400 fp16
    const size_t need_fast = (64 + n_depth) * sizeof(float) + n_feat * sizeof(_Float16);

    float* mats   = (float*)d_ws;
    float* depthT = mats + 64;

    if (ws_size >= need_fast) {
        _Float16* featT = (_Float16*)(depthT + n_depth);   // 16B-aligned
        prep_fast<<<dim3(NB_SOFT + NB_TR), dim3(256), 0, stream>>>(
            feat, K, E, mats, depthT, featT);
        lift_fast<<<dim3(NPTS / 256, NCHUNK), dim3(256), 0, stream>>>(
            featT, E, mats, depthT, out);
    } else {
        // proven R1 path: depth in [s][d][pix] layout, gather from original feat
        prep_fb<<<dim3((S_CAMS * PIX + 255) / 256), dim3(256), 0, stream>>>(
            feat, K, E, mats, depthT);
        lift_fb<<<dim3(NPTS / 256, NCHUNK), dim3(256), 0, stream>>>(
            feat, E, mats, depthT, out);
    }
}

// Round 5
// 98.716 us; speedup vs baseline: 1.7109x; 1.2949x over previous
//
#include <hip/hip_runtime.h>

#define S_CAMS 4
#define D_BINS 32
#define CFEAT  96
#define HFD    45
#define WFD    80
#define PIX    (HFD*WFD)        // 3600
#define CHW    (128*PIX)        // per-camera input stride (128 channels)
#define YD     128
#define ZD     8
#define XD     128
#define NPTS   (YD*ZD*XD)       // 131072

#define NB_SOFT 57              // ceil(4*3600/256) softmax blocks
#define NB_TR   675             // 4*12*3600/256 fp16-transpose blocks

typedef _Float16 h8 __attribute__((ext_vector_type(8)));   // 16 B

// ---------------- FAST PATH (~4.6 MB ws) ----------------
// Fused prep: blocks [0,NB_SOFT): mats = K@E + per-pixel softmax over 32
// depth logits -> depth[s][t][pix] f32 (pixel-minor, so corner taps of
// consecutive voxels coalesce). blocks [NB_SOFT,..): transpose+cast feat ->
// featT[s][pix][96] fp16 (pixel base 192 B = 64B-aligned).
__global__ void prep_fast(const float* __restrict__ feat,
                          const float* __restrict__ K,
                          const float* __restrict__ E,
                          float* __restrict__ mats,
                          float* __restrict__ depth,
                          _Float16* __restrict__ featT) {
    int b = blockIdx.x;
    if (b < NB_SOFT) {
        int tid = b * 256 + threadIdx.x;
        if (tid < S_CAMS * 16) {
            int s = tid >> 4, ij = tid & 15;
            int i = ij >> 2, j = ij & 3;
            const float* Ks = K + s * 16;
            const float* Es = E + s * 16;
            float acc = 0.f;
            #pragma unroll
            for (int k = 0; k < 4; ++k) acc += Ks[i*4+k] * Es[k*4+j];
            mats[tid] = acc;
        }
        if (tid < S_CAMS * PIX) {
            int s = tid / PIX;
            int p = tid - s * PIX;
            const float* base = feat + s * CHW + p;   // ch 0..31 = depth logits
            float v[D_BINS];
            float m = -3.4e38f;
            #pragma unroll
            for (int d = 0; d < D_BINS; ++d) {
                v[d] = base[d * PIX];
                m = fmaxf(m, v[d]);
            }
            float sum = 0.f;
            #pragma unroll
            for (int d = 0; d < D_BINS; ++d) {
                v[d] = __expf(v[d] - m);
                sum += v[d];
            }
            float inv = 1.f / sum;
            float* dst = depth + s * (D_BINS * PIX) + p;   // [t][pix] strided
            #pragma unroll
            for (int d = 0; d < D_BINS; ++d) dst[d * PIX] = v[d] * inv;
        }
    } else {
        int t = (b - NB_SOFT) * 256 + threadIdx.x;   // < 4*12*3600 exactly
        int s  = t / (12 * PIX);
        int r  = t - s * (12 * PIX);
        int c8 = r / PIX;
        int p  = r - c8 * PIX;
        const float* src = feat + s * CHW + (D_BINS + c8 * 8) * PIX + p;
        h8 o;
        #pragma unroll
        for (int i = 0; i < 8; ++i) o[i] = (_Float16)src[i * PIX];
        ((h8*)featT)[(size_t)(s * PIX + p) * 12 + c8] = o;
    }
}

// Main (fast): 4 lanes per voxel (wave = 16 voxels x 4 subs). Weight phase is
// computed redundantly by the 4 subs (identical -> addresses coalesce). Clamps
// are remapped to an in-bounds 2x2x2 base + reassigned weights (uwA/uwB etc.),
// exactly equal to reference clamp+mask semantics. Feature phase: per corner,
// sub-lane loads its 16 B quarter of the pixel's 192 B channel row -> each
// 64 B line fully consumed by a 4-lane group.
__global__ __launch_bounds__(256, 4) void lift_fast(
    const _Float16* __restrict__ featT,
    const float* __restrict__ E,
    const float* __restrict__ mats,
    const float* __restrict__ depth,    // [s][32][PIX] f32
    float* __restrict__ out) {
    int t = blockIdx.x * 256 + threadIdx.x;
    int sub = t & 3;
    int vox = t >> 2;
    int xi = vox & (XD - 1);
    int zi = (vox >> 7) & (ZD - 1);
    int yi = vox >> 10;

    float xw = -25.f + (xi + 0.5f) * (50.f / XD);
    float yw = -25.f + (yi + 0.5f) * (50.f / YD);
    float zw = (zi + 0.5f) * 0.5f;

    float w[16];
    int   off[16];          // h8 index: (s*PIX+p)*12 + sub
    float one_sum = 0.f;

    #pragma unroll
    for (int s = 0; s < S_CAMS; ++s) {
        const float* P  = mats + s * 16;
        const float* Es = E + s * 16;
        float zcam = Es[8]*xw + Es[9]*yw + Es[10]*zw + Es[11];
        float px = P[0]*xw + P[1]*yw + P[2]*zw  + P[3];
        float py = P[4]*xw + P[5]*yw + P[6]*zw  + P[7];
        float pz = P[8]*xw + P[9]*yw + P[10]*zw + P[11];
        float zc = fmaxf(pz, 1e-6f);
        float xp = px / zc;
        float yp = py / zc;
        float zt = (float)(D_BINS - 1) * (zcam - 2.f) * (1.f / 30.f);
        float vmask = (xp > -0.5f && xp < (float)WFD - 0.5f &&
                       yp > -0.5f && yp < (float)HFD - 0.5f &&
                       zcam > 0.f) ? 1.f : 0.f;
        float us = xp * ((float)WFD / (WFD - 1)) - 0.5f;
        float vs = yp * ((float)HFD / (HFD - 1)) - 0.5f;
        float ts = zt * ((float)D_BINS / (D_BINS - 1)) - 0.5f;
        float u0f = floorf(us), v0f = floorf(vs), t0f = floorf(ts);
        float fu = us - u0f, fv = vs - v0f, ft = ts - t0f;
        int u0 = (int)u0f, v0 = (int)v0f, tz = (int)t0f;
        // range-masked raw weights (mask folded in)
        float uw0 = (u0 >= 0     && u0 < WFD)      ? (1.f - fu) : 0.f;
        float uw1 = (u0 + 1 >= 0 && u0 + 1 < WFD)  ? fu         : 0.f;
        float vw0 = (v0 >= 0     && v0 < HFD)      ? (1.f - fv) : 0.f;
        float vw1 = (v0 + 1 >= 0 && v0 + 1 < HFD)  ? fv         : 0.f;
        float tw0 = (tz >= 0     && tz < D_BINS)   ? (1.f - ft) : 0.f;
        float tw1 = (tz + 1 >= 0 && tz + 1 < D_BINS) ? ft       : 0.f;
        // in-bounds 2x2x2 base + weight remap (== reference clamp+mask)
        int bu = min(max(u0, 0), WFD - 2);
        int bv = min(max(v0, 0), HFD - 2);
        int bt = min(max(tz, 0), D_BINS - 2);
        float uwA = (u0 == bu) ? uw0 : ((u0 == bu - 1) ? uw1 : 0.f);
        float uwB = (u0 == bu) ? uw1 : ((u0 == bu + 1) ? uw0 : 0.f);
        float vwA = (v0 == bv) ? vw0 : ((v0 == bv - 1) ? vw1 : 0.f);
        float vwB = (v0 == bv) ? vw1 : ((v0 == bv + 1) ? vw0 : 0.f);
        float twA = (tz == bt) ? tw0 : ((tz == bt - 1) ? tw1 : 0.f);
        float twB = (tz == bt) ? tw1 : ((tz == bt + 1) ? tw0 : 0.f);
        int pb = bv * WFD + bu;
        const float* dp0 = depth + (s * D_BINS + bt) * PIX + pb;
        const float* dp1 = dp0 + PIX;
        float gAA = twA * dp0[0]       + twB * dp1[0];
        float gAB = twA * dp0[1]       + twB * dp1[1];
        float gBA = twA * dp0[WFD]     + twB * dp1[WFD];
        float gBB = twA * dp0[WFD + 1] + twB * dp1[WFD + 1];
        float wsum_hw = (vwA + vwB) * (uwA + uwB);
        float one_s = fmaxf(vmask * (twA + twB) * wsum_hw, 1.f);
        one_sum += one_s;
        float sc = vmask * one_s;
        w[s*4+0] = sc * vwA * uwA * gAA;
        w[s*4+1] = sc * vwA * uwB * gAB;
        w[s*4+2] = sc * vwB * uwA * gBA;
        w[s*4+3] = sc * vwB * uwB * gBB;
        int pixbase = s * PIX + pb;
        off[s*4+0] = pixbase * 12 + sub;
        off[s*4+1] = (pixbase + 1) * 12 + sub;
        off[s*4+2] = (pixbase + WFD) * 12 + sub;
        off[s*4+3] = (pixbase + WFD + 1) * 12 + sub;
    }

    float inv = 1.f / (1e-6f + one_sum);
    #pragma unroll
    for (int k = 0; k < 16; ++k) w[k] *= inv;

    float acc[24];
    #pragma unroll
    for (int j = 0; j < 24; ++j) acc[j] = 0.f;

    const h8* fT = (const h8*)featT;
    #pragma unroll 4
    for (int k = 0; k < 16; ++k) {
        float wk = w[k];
        #pragma unroll
        for (int j = 0; j < 3; ++j) {
            h8 v = fT[off[k] + 4 * j];
            #pragma unroll
            for (int i = 0; i < 8; ++i)
                acc[j*8+i] = fmaf(wk, (float)v[i], acc[j*8+i]);
        }
    }

    int outsp = yi * XD + xi;
    #pragma unroll
    for (int j = 0; j < 3; ++j) {
        #pragma unroll
        for (int i = 0; i < 8; ++i) {
            int c = j * 32 + sub * 8 + i;   // channel owned by this lane
            __builtin_nontemporal_store(acc[j*8+i],
                &out[(c * ZD + zi) * (YD * XD) + outsp]);
        }
    }
}

// ---------------- FALLBACK PATH (R1, proven, ~1.84 MB ws) ----------------
__global__ void prep_fb(const float* __restrict__ feat,
                        const float* __restrict__ K,
                        const float* __restrict__ E,
                        float* __restrict__ mats,
                        float* __restrict__ depth) {
    int tid = blockIdx.x * blockDim.x + threadIdx.x;
    if (tid < S_CAMS * 16) {
        int s = tid >> 4, ij = tid & 15;
        int i = ij >> 2, j = ij & 3;
        const float* Ks = K + s * 16;
        const float* Es = E + s * 16;
        float acc = 0.f;
        #pragma unroll
        for (int k = 0; k < 4; ++k) acc += Ks[i*4+k] * Es[k*4+j];
        mats[tid] = acc;
    }
    if (tid < S_CAMS * PIX) {
        int s = tid / PIX;
        int p = tid - s * PIX;
        const float* base = feat + s * CHW + p;
        float v[D_BINS];
        float m = -3.4e38f;
        #pragma unroll
        for (int d = 0; d < D_BINS; ++d) {
            v[d] = base[d * PIX];
            m = fmaxf(m, v[d]);
        }
        float sum = 0.f;
        #pragma unroll
        for (int d = 0; d < D_BINS; ++d) {
            v[d] = __expf(v[d] - m);
            sum += v[d];
        }
        float inv = 1.f / sum;
        float* dst = depth + s * (D_BINS * PIX) + p;
        #pragma unroll
        for (int d = 0; d < D_BINS; ++d) dst[d * PIX] = v[d] * inv;
    }
}

__global__ __launch_bounds__(256) void lift_fb(
    const float* __restrict__ feat,
    const float* __restrict__ E,
    const float* __restrict__ mats,
    const float* __restrict__ depth,
    float* __restrict__ out) {
    int tid = blockIdx.x * 256 + threadIdx.x;
    int xi = tid & (XD - 1);
    int zi = (tid >> 7) & (ZD - 1);
    int yi = tid >> 10;

    float xw = -25.f + (xi + 0.5f) * (50.f / XD);
    float yw = -25.f + (yi + 0.5f) * (50.f / YD);
    float zw = (zi + 0.5f) * 0.5f;

    float w[16];
    int   off[16];
    float one_sum = 0.f;

    #pragma unroll
    for (int s = 0; s < S_CAMS; ++s) {
        const float* P  = mats + s * 16;
        const float* Es = E + s * 16;
        float zcam = Es[8]*xw + Es[9]*yw + Es[10]*zw + Es[11];
        float px = P[0]*xw + P[1]*yw + P[2]*zw  + P[3];
        float py = P[4]*xw + P[5]*yw + P[6]*zw  + P[7];
        float pz = P[8]*xw + P[9]*yw + P[10]*zw + P[11];
        float zc = fmaxf(pz, 1e-6f);
        float xp = px / zc;
        float yp = py / zc;
        float zt = (float)(D_BINS - 1) * (zcam - 2.f) * (1.f / 30.f);
        float vmask = (xp > -0.5f && xp < (float)WFD - 0.5f &&
                       yp > -0.5f && yp < (float)HFD - 0.5f &&
                       zcam > 0.f) ? 1.f : 0.f;
        float us = xp * ((float)WFD / (WFD - 1)) - 0.5f;
        float vs = yp * ((float)HFD / (HFD - 1)) - 0.5f;
        float ts = zt * ((float)D_BINS / (D_BINS - 1)) - 0.5f;
        float u0f = floorf(us), v0f = floorf(vs), t0f = floorf(ts);
        float fu = us - u0f, fv = vs - v0f, ft = ts - t0f;
        int u0 = (int)u0f, v0 = (int)v0f, t0 = (int)t0f;
        int u1 = u0 + 1, v1 = v0 + 1, t1 = t0 + 1;
        float wu0 = 1.f - fu, wu1 = fu;
        float wv0 = 1.f - fv, wv1 = fv;
        float wz0 = (t0 >= 0 && t0 < D_BINS) ? (1.f - ft) : 0.f;
        float wz1 = (t1 >= 0 && t1 < D_BINS) ? ft : 0.f;
        float mu0 = (u0 >= 0 && u0 < WFD) ? 1.f : 0.f;
        float mu1 = (u1 >= 0 && u1 < WFD) ? 1.f : 0.f;
        float mv0 = (v0 >= 0 && v0 < HFD) ? 1.f : 0.f;
        float mv1 = (v1 >= 0 && v1 < HFD) ? 1.f : 0.f;
        int u0c = min(max(u0, 0), WFD - 1), u1c = min(max(u1, 0), WFD - 1);
        int v0c = min(max(v0, 0), HFD - 1), v1c = min(max(v1, 0), HFD - 1);
        int t0c = min(max(t0, 0), D_BINS - 1), t1c = min(max(t1, 0), D_BINS - 1);
        int p00 = v0c * WFD + u0c, p01 = v0c * WFD + u1c;
        int p10 = v1c * WFD + u0c, p11 = v1c * WFD + u1c;
        const float* dep0 = depth + s * (D_BINS * PIX) + t0c * PIX;
        const float* dep1 = depth + s * (D_BINS * PIX) + t1c * PIX;
        float g00 = wz0 * dep0[p00] + wz1 * dep1[p00];
        float g01 = wz0 * dep0[p01] + wz1 * dep1[p01];
        float g10 = wz0 * dep0[p10] + wz1 * dep1[p10];
        float g11 = wz0 * dep0[p11] + wz1 * dep1[p11];
        float m00 = mv0 * mu0, m01 = mv0 * mu1, m10 = mv1 * mu0, m11 = mv1 * mu1;
        float ws00 = wv0 * wu0 * m00, ws01 = wv0 * wu1 * m01;
        float ws10 = wv1 * wu0 * m10, ws11 = wv1 * wu1 * m11;
        float wsum_hw = ws00 + ws01 + ws10 + ws11;
        float one_s = fmaxf(vmask * (wz0 + wz1) * wsum_hw, 1.f);
        one_sum += one_s;
        float sc = vmask * one_s;
        w[s*4+0] = sc * ws00 * g00;
        w[s*4+1] = sc * ws01 * g01;
        w[s*4+2] = sc * ws10 * g10;
        w[s*4+3] = sc * ws11 * g11;
        int base = s * CHW;
        off[s*4+0] = base + p00;
        off[s*4+1] = base + p01;
        off[s*4+2] = base + p10;
        off[s*4+3] = base + p11;
    }

    float inv = 1.f / (1e-6f + one_sum);
    #pragma unroll
    for (int k = 0; k < 16; ++k) w[k] *= inv;

    int c0 = blockIdx.y * 24;
    int outsp = yi * XD + xi;
    for (int c = c0; c < c0 + 24; ++c) {
        const float* fp = feat + (D_BINS + c) * PIX;
        float acc = 0.f;
        #pragma unroll
        for (int k = 0; k < 16; ++k) acc = fmaf(w[k], fp[off[k]], acc);
        out[(c * ZD + zi) * (YD * XD) + outsp] = acc;
    }
}

extern "C" void kernel_launch(void* const* d_in, const int* in_sizes, int n_in,
                              void* d_out, int out_size, void* d_ws, size_t ws_size,
                              hipStream_t stream) {
    const float* feat = (const float*)d_in[0];   // (4,128,45,80) f32
    const float* K    = (const float*)d_in[1];   // (4,4,4) f32
    const float* E    = (const float*)d_in[2];   // (4,4,4) f32
    float* out  = (float*)d_out;                 // (1,768,128,128) f32

    const size_t n_depth = (size_t)S_CAMS * PIX * D_BINS;   // 460800 f32
    const size_t n_feat  = (size_t)S_CAMS * PIX * CFEAT;    // 1382400 fp16
    const size_t need_fast = (64 + n_depth) * sizeof(float) + n_feat * sizeof(_Float16);

    float* mats  = (float*)d_ws;
    float* depth = mats + 64;

    if (ws_size >= need_fast) {
        _Float16* featT = (_Float16*)(depth + n_depth);   // 64B-aligned
        prep_fast<<<dim3(NB_SOFT + NB_TR), dim3(256), 0, stream>>>(
            feat, K, E, mats, depth, featT);
        lift_fast<<<dim3(NPTS * 4 / 256), dim3(256), 0, stream>>>(
            featT, E, mats, depth, out);
    } else {
        // proven R1 path: depth in [s][t][pix] layout, gather from original feat
        prep_fb<<<dim3((S_CAMS * PIX + 255) / 256), dim3(256), 0, stream>>>(
            feat, K, E, mats, depth);
        lift_fb<<<dim3(NPTS / 256, 4), dim3(256), 0, stream>>>(
            feat, E, mats, depth, out);
    }
}

// Round 6
// 95.850 us; speedup vs baseline: 1.7621x; 1.0299x over previous
//
#include <hip/hip_runtime.h>

#define S_CAMS 4
#define D_BINS 32
#define CFEAT  96
#define HFD    45
#define WFD    80
#define PIX    (HFD*WFD)        // 3600
#define CHW    (128*PIX)        // per-camera input stride (128 channels)
#define YD     128
#define ZD     8
#define XD     128
#define NPTS   (YD*ZD*XD)       // 131072

#define NB_SOFT 57              // ceil(4*3600/256) softmax blocks
#define NB_TR   675             // 4*12*3600/256 fp16-transpose blocks

typedef _Float16 h8 __attribute__((ext_vector_type(8)));   // 16 B

// ---------------- FAST PATH (~4.6 MB ws) ----------------
// Fused prep: blocks [0,NB_SOFT): mats = K@E + per-pixel softmax over 32
// depth logits -> depth[s][t][pix] f32. blocks [NB_SOFT,..): transpose+cast
// feat -> featT[s][pix][96] fp16 (pixel base 192 B = 64B-aligned).
__global__ void prep_fast(const float* __restrict__ feat,
                          const float* __restrict__ K,
                          const float* __restrict__ E,
                          float* __restrict__ mats,
                          float* __restrict__ depth,
                          _Float16* __restrict__ featT) {
    int b = blockIdx.x;
    if (b < NB_SOFT) {
        int tid = b * 256 + threadIdx.x;
        if (tid < S_CAMS * 16) {
            int s = tid >> 4, ij = tid & 15;
            int i = ij >> 2, j = ij & 3;
            const float* Ks = K + s * 16;
            const float* Es = E + s * 16;
            float acc = 0.f;
            #pragma unroll
            for (int k = 0; k < 4; ++k) acc += Ks[i*4+k] * Es[k*4+j];
            mats[tid] = acc;
        }
        if (tid < S_CAMS * PIX) {
            int s = tid / PIX;
            int p = tid - s * PIX;
            const float* base = feat + s * CHW + p;   // ch 0..31 = depth logits
            float v[D_BINS];
            float m = -3.4e38f;
            #pragma unroll
            for (int d = 0; d < D_BINS; ++d) {
                v[d] = base[d * PIX];
                m = fmaxf(m, v[d]);
            }
            float sum = 0.f;
            #pragma unroll
            for (int d = 0; d < D_BINS; ++d) {
                v[d] = __expf(v[d] - m);
                sum += v[d];
            }
            float inv = 1.f / sum;
            float* dst = depth + s * (D_BINS * PIX) + p;   // [t][pix] strided
            #pragma unroll
            for (int d = 0; d < D_BINS; ++d) dst[d * PIX] = v[d] * inv;
        }
    } else {
        int t = (b - NB_SOFT) * 256 + threadIdx.x;   // < 4*12*3600 exactly
        int s  = t / (12 * PIX);
        int r  = t - s * (12 * PIX);
        int c8 = r / PIX;
        int p  = r - c8 * PIX;
        const float* src = feat + s * CHW + (D_BINS + c8 * 8) * PIX + p;
        h8 o;
        #pragma unroll
        for (int i = 0; i < 8; ++i) o[i] = (_Float16)src[i * PIX];
        ((h8*)featT)[(size_t)(s * PIX + p) * 12 + c8] = o;
    }
}

// Main (fast): 4 lanes per voxel (wave = 16 voxels x 4 subs).
// Weight phase DISTRIBUTED: sub-lane s computes camera s only (VALU/4,
// depth VMEM 32->8 per thread), then width-4 shuffles broadcast the 16
// (w, off) pairs and butterfly-reduce one_sum across the group.
// Clamps remapped to in-bounds 2x2x2 base + reassigned weights (uwA/uwB
// etc.), exactly equal to reference clamp+mask semantics. Feature phase:
// per corner, sub-lane loads its 16 B quarter of the pixel's 192 B channel
// row -> each 64 B line fully consumed by a 4-lane group.
__global__ __launch_bounds__(256, 4) void lift_fast(
    const _Float16* __restrict__ featT,
    const float* __restrict__ E,
    const float* __restrict__ mats,
    const float* __restrict__ depth,    // [s][32][PIX] f32
    float* __restrict__ out) {
    int t = blockIdx.x * 256 + threadIdx.x;
    int sub = t & 3;
    int vox = t >> 2;
    int xi = vox & (XD - 1);
    int zi = (vox >> 7) & (ZD - 1);
    int yi = vox >> 10;

    float xw = -25.f + (xi + 0.5f) * (50.f / XD);
    float yw = -25.f + (yi + 0.5f) * (50.f / YD);
    float zw = (zi + 0.5f) * 0.5f;

    // ---- weight phase: this lane handles camera s == sub ----
    float w4[4];
    int   off4[4];          // h8 index (without +sub)
    float one_s;
    {
        int s = sub;
        const float* P  = mats + s * 16;
        const float* Es = E + s * 16;
        float zcam = Es[8]*xw + Es[9]*yw + Es[10]*zw + Es[11];
        float px = P[0]*xw + P[1]*yw + P[2]*zw  + P[3];
        float py = P[4]*xw + P[5]*yw + P[6]*zw  + P[7];
        float pz = P[8]*xw + P[9]*yw + P[10]*zw + P[11];
        float zc = fmaxf(pz, 1e-6f);
        float xp = px / zc;
        float yp = py / zc;
        float zt = (float)(D_BINS - 1) * (zcam - 2.f) * (1.f / 30.f);
        float vmask = (xp > -0.5f && xp < (float)WFD - 0.5f &&
                       yp > -0.5f && yp < (float)HFD - 0.5f &&
                       zcam > 0.f) ? 1.f : 0.f;
        float us = xp * ((float)WFD / (WFD - 1)) - 0.5f;
        float vs = yp * ((float)HFD / (HFD - 1)) - 0.5f;
        float ts = zt * ((float)D_BINS / (D_BINS - 1)) - 0.5f;
        float u0f = floorf(us), v0f = floorf(vs), t0f = floorf(ts);
        float fu = us - u0f, fv = vs - v0f, ft = ts - t0f;
        int u0 = (int)u0f, v0 = (int)v0f, tz = (int)t0f;
        float uw0 = (u0 >= 0     && u0 < WFD)      ? (1.f - fu) : 0.f;
        float uw1 = (u0 + 1 >= 0 && u0 + 1 < WFD)  ? fu         : 0.f;
        float vw0 = (v0 >= 0     && v0 < HFD)      ? (1.f - fv) : 0.f;
        float vw1 = (v0 + 1 >= 0 && v0 + 1 < HFD)  ? fv         : 0.f;
        float tw0 = (tz >= 0     && tz < D_BINS)   ? (1.f - ft) : 0.f;
        float tw1 = (tz + 1 >= 0 && tz + 1 < D_BINS) ? ft       : 0.f;
        int bu = min(max(u0, 0), WFD - 2);
        int bv = min(max(v0, 0), HFD - 2);
        int bt = min(max(tz, 0), D_BINS - 2);
        float uwA = (u0 == bu) ? uw0 : ((u0 == bu - 1) ? uw1 : 0.f);
        float uwB = (u0 == bu) ? uw1 : ((u0 == bu + 1) ? uw0 : 0.f);
        float vwA = (v0 == bv) ? vw0 : ((v0 == bv - 1) ? vw1 : 0.f);
        float vwB = (v0 == bv) ? vw1 : ((v0 == bv + 1) ? vw0 : 0.f);
        float twA = (tz == bt) ? tw0 : ((tz == bt - 1) ? tw1 : 0.f);
        float twB = (tz == bt) ? tw1 : ((tz == bt + 1) ? tw0 : 0.f);
        int pb = bv * WFD + bu;
        const float* dp0 = depth + (s * D_BINS + bt) * PIX + pb;
        const float* dp1 = dp0 + PIX;
        float gAA = twA * dp0[0]       + twB * dp1[0];
        float gAB = twA * dp0[1]       + twB * dp1[1];
        float gBA = twA * dp0[WFD]     + twB * dp1[WFD];
        float gBB = twA * dp0[WFD + 1] + twB * dp1[WFD + 1];
        float wsum_hw = (vwA + vwB) * (uwA + uwB);
        one_s = fmaxf(vmask * (twA + twB) * wsum_hw, 1.f);
        float sc = vmask * one_s;
        w4[0] = sc * vwA * uwA * gAA;
        w4[1] = sc * vwA * uwB * gAB;
        w4[2] = sc * vwB * uwA * gBA;
        w4[3] = sc * vwB * uwB * gBB;
        int pixbase = s * PIX + pb;
        off4[0] = pixbase * 12;
        off4[1] = (pixbase + 1) * 12;
        off4[2] = (pixbase + WFD) * 12;
        off4[3] = (pixbase + WFD + 1) * 12;
    }

    // group reduction of one_sum (4 lanes per voxel)
    float one_sum = one_s;
    one_sum += __shfl_xor(one_sum, 1, 4);
    one_sum += __shfl_xor(one_sum, 2, 4);
    float inv = 1.f / (1e-6f + one_sum);
    #pragma unroll
    for (int c = 0; c < 4; ++c) w4[c] *= inv;

    // broadcast all 16 (w, off) pairs to every lane of the group
    float w[16];
    int   off[16];
    #pragma unroll
    for (int s2 = 0; s2 < 4; ++s2) {
        #pragma unroll
        for (int c = 0; c < 4; ++c) {
            w[s2*4+c]   = __shfl(w4[c], s2, 4);
            off[s2*4+c] = __shfl(off4[c], s2, 4) + sub;
        }
    }

    float acc[24];
    #pragma unroll
    for (int j = 0; j < 24; ++j) acc[j] = 0.f;

    const h8* fT = (const h8*)featT;
    #pragma unroll 4
    for (int k = 0; k < 16; ++k) {
        float wk = w[k];
        #pragma unroll
        for (int j = 0; j < 3; ++j) {
            h8 v = fT[off[k] + 4 * j];
            #pragma unroll
            for (int i = 0; i < 8; ++i)
                acc[j*8+i] = fmaf(wk, (float)v[i], acc[j*8+i]);
        }
    }

    int outsp = yi * XD + xi;
    #pragma unroll
    for (int j = 0; j < 3; ++j) {
        #pragma unroll
        for (int i = 0; i < 8; ++i) {
            int c = j * 32 + sub * 8 + i;   // channel owned by this lane
            __builtin_nontemporal_store(acc[j*8+i],
                &out[(c * ZD + zi) * (YD * XD) + outsp]);
        }
    }
}

// ---------------- FALLBACK PATH (R1, proven, ~1.84 MB ws) ----------------
__global__ void prep_fb(const float* __restrict__ feat,
                        const float* __restrict__ K,
                        const float* __restrict__ E,
                        float* __restrict__ mats,
                        float* __restrict__ depth) {
    int tid = blockIdx.x * blockDim.x + threadIdx.x;
    if (tid < S_CAMS * 16) {
        int s = tid >> 4, ij = tid & 15;
        int i = ij >> 2, j = ij & 3;
        const float* Ks = K + s * 16;
        const float* Es = E + s * 16;
        float acc = 0.f;
        #pragma unroll
        for (int k = 0; k < 4; ++k) acc += Ks[i*4+k] * Es[k*4+j];
        mats[tid] = acc;
    }
    if (tid < S_CAMS * PIX) {
        int s = tid / PIX;
        int p = tid - s * PIX;
        const float* base = feat + s * CHW + p;
        float v[D_BINS];
        float m = -3.4e38f;
        #pragma unroll
        for (int d = 0; d < D_BINS; ++d) {
            v[d] = base[d * PIX];
            m = fmaxf(m, v[d]);
        }
        float sum = 0.f;
        #pragma unroll
        for (int d = 0; d < D_BINS; ++d) {
            v[d] = __expf(v[d] - m);
            sum += v[d];
        }
        float inv = 1.f / sum;
        float* dst = depth + s * (D_BINS * PIX) + p;
        #pragma unroll
        for (int d = 0; d < D_BINS; ++d) dst[d * PIX] = v[d] * inv;
    }
}

__global__ __launch_bounds__(256) void lift_fb(
    const float* __restrict__ feat,
    const float* __restrict__ E,
    const float* __restrict__ mats,
    const float* __restrict__ depth,
    float* __restrict__ out) {
    int tid = blockIdx.x * 256 + threadIdx.x;
    int xi = tid & (XD - 1);
    int zi = (tid >> 7) & (ZD - 1);
    int yi = tid >> 10;

    float xw = -25.f + (xi + 0.5f) * (50.f / XD);
    float yw = -25.f + (yi + 0.5f) * (50.f / YD);
    float zw = (zi + 0.5f) * 0.5f;

    float w[16];
    int   off[16];
    float one_sum = 0.f;

    #pragma unroll
    for (int s = 0; s < S_CAMS; ++s) {
        const float* P  = mats + s * 16;
        const float* Es = E + s * 16;
        float zcam = Es[8]*xw + Es[9]*yw + Es[10]*zw + Es[11];
        float px = P[0]*xw + P[1]*yw + P[2]*zw  + P[3];
        float py = P[4]*xw + P[5]*yw + P[6]*zw  + P[7];
        float pz = P[8]*xw + P[9]*yw + P[10]*zw + P[11];
        float zc = fmaxf(pz, 1e-6f);
        float xp = px / zc;
        float yp = py / zc;
        float zt = (float)(D_BINS - 1) * (zcam - 2.f) * (1.f / 30.f);
        float vmask = (xp > -0.5f && xp < (float)WFD - 0.5f &&
                       yp > -0.5f && yp < (float)HFD - 0.5f &&
                       zcam > 0.f) ? 1.f : 0.f;
        float us = xp * ((float)WFD / (WFD - 1)) - 0.5f;
        float vs = yp * ((float)HFD / (HFD - 1)) - 0.5f;
        float ts = zt * ((float)D_BINS / (D_BINS - 1)) - 0.5f;
        float u0f = floorf(us), v0f = floorf(vs), t0f = floorf(ts);
        float fu = us - u0f, fv = vs - v0f, ft = ts - t0f;
        int u0 = (int)u0f, v0 = (int)v0f, t0 = (int)t0f;
        int u1 = u0 + 1, v1 = v0 + 1, t1 = t0 + 1;
        float wu0 = 1.f - fu, wu1 = fu;
        float wv0 = 1.f - fv, wv1 = fv;
        float wz0 = (t0 >= 0 && t0 < D_BINS) ? (1.f - ft) : 0.f;
        float wz1 = (t1 >= 0 && t1 < D_BINS) ? ft : 0.f;
        float mu0 = (u0 >= 0 && u0 < WFD) ? 1.f : 0.f;
        float mu1 = (u1 >= 0 && u1 < WFD) ? 1.f : 0.f;
        float mv0 = (v0 >= 0 && v0 < HFD) ? 1.f : 0.f;
        float mv1 = (v1 >= 0 && v1 < HFD) ? 1.f : 0.f;
        int u0c = min(max(u0, 0), WFD - 1), u1c = min(max(u1, 0), WFD - 1);
        int v0c = min(max(v0, 0), HFD - 1), v1c = min(max(v1, 0), HFD - 1);
        int t0c = min(max(t0, 0), D_BINS - 1), t1c = min(max(t1, 0), D_BINS - 1);
        int p00 = v0c * WFD + u0c, p01 = v0c * WFD + u1c;
        int p10 = v1c * WFD + u0c, p11 = v1c * WFD + u1c;
        const float* dep0 = depth + s * (D_BINS * PIX) + t0c * PIX;
        const float* dep1 = depth + s * (D_BINS * PIX) + t1c * PIX;
        float g00 = wz0 * dep0[p00] + wz1 * dep1[p00];
        float g01 = wz0 * dep0[p01] + wz1 * dep1[p01];
        float g10 = wz0 * dep0[p10] + wz1 * dep1[p10];
        float g11 = wz0 * dep0[p11] + wz1 * dep1[p11];
        float m00 = mv0 * mu0, m01 = mv0 * mu1, m10 = mv1 * mu0, m11 = mv1 * mu1;
        float ws00 = wv0 * wu0 * m00, ws01 = wv0 * wu1 * m01;
        float ws10 = wv1 * wu0 * m10, ws11 = wv1 * wu1 * m11;
        float wsum_hw = ws00 + ws01 + ws10 + ws11;
        float one_s = fmaxf(vmask * (wz0 + wz1) * wsum_hw, 1.f);
        one_sum += one_s;
        float sc = vmask * one_s;
        w[s*4+0] = sc * ws00 * g00;
        w[s*4+1] = sc * ws01 * g01;
        w[s*4+2] = sc * ws10 * g10;
        w[s*4+3] = sc * ws11 * g11;
        int base = s * CHW;
        off[s*4+0] = base + p00;
        off[s*4+1] = base + p01;
        off[s*4+2] = base + p10;
        off[s*4+3] = base + p11;
    }

    float inv = 1.f / (1e-6f + one_sum);
    #pragma unroll
    for (int k = 0; k < 16; ++k) w[k] *= inv;

    int c0 = blockIdx.y * 24;
    int outsp = yi * XD + xi;
    for (int c = c0; c < c0 + 24; ++c) {
        const float* fp = feat + (D_BINS + c) * PIX;
        float acc = 0.f;
        #pragma unroll
        for (int k = 0; k < 16; ++k) acc = fmaf(w[k], fp[off[k]], acc);
        out[(c * ZD + zi) * (YD * XD) + outsp] = acc;
    }
}

extern "C" void kernel_launch(void* const* d_in, const int* in_sizes, int n_in,
                              void* d_out, int out_size, void* d_ws, size_t ws_size,
                              hipStream_t stream) {
    const float* feat = (const float*)d_in[0];   // (4,128,45,80) f32
    const float* K    = (const float*)d_in[1];   // (4,4,4) f32
    const float* E    = (const float*)d_in[2];   // (4,4,4) f32
    float* out  = (float*)d_out;                 // (1,768,128,128) f32

    const size_t n_depth = (size_t)S_CAMS * PIX * D_BINS;   // 460800 f32
    const size_t n_feat  = (size_t)S_CAMS * PIX * CFEAT;    // 1382400 fp16
    const size_t need_fast = (64 + n_depth) * sizeof(float) + n_feat * sizeof(_Float16);

    float* mats  = (float*)d_ws;
    float* depth = mats + 64;

    if (ws_size >= need_fast) {
        _Float16* featT = (_Float16*)(depth + n_depth);   // 64B-aligned
        prep_fast<<<dim3(NB_SOFT + NB_TR), dim3(256), 0, stream>>>(
            feat, K, E, mats, depth, featT);
        lift_fast<<<dim3(NPTS * 4 / 256), dim3(256), 0, stream>>>(
            featT, E, mats, depth, out);
    } else {
        // proven R1 path: depth in [s][t][pix] layout, gather from original feat
        prep_fb<<<dim3((S_CAMS * PIX + 255) / 256), dim3(256), 0, stream>>>(
            feat, K, E, mats, depth);
        lift_fb<<<dim3(NPTS / 256, 4), dim3(256), 0, stream>>>(
            feat, E, mats, depth, out);
    }
}

// Round 7
// 89.655 us; speedup vs baseline: 1.8838x; 1.0691x over previous
//
#include <hip/hip_runtime.h>

#define S_CAMS 4
#define D_BINS 32
#define CFEAT  96
#define HFD    45
#define WFD    80
#define PIX    (HFD*WFD)        // 3600
#define CHW    (128*PIX)        // per-camera input stride (128 channels)
#define YD     128
#define ZD     8
#define XD     128
#define NPTS   (YD*ZD*XD)       // 131072

#define NB_SOFT 57              // ceil(4*3600/256) softmax blocks
#define NB_TR   675             // 4*12*3600/256 fp16-transpose blocks

typedef _Float16 h8 __attribute__((ext_vector_type(8)));   // 16 B

// ---------------- FAST PATH (~4.6 MB ws) ----------------
// Fused prep: blocks [0,NB_SOFT): mats = K@E + per-pixel softmax over 32
// depth logits -> depth[s][t][pix] f32. blocks [NB_SOFT,..): transpose+cast
// feat -> featT[s][pix][96] fp16 (pixel base 192 B = 64B-aligned).
__global__ void prep_fast(const float* __restrict__ feat,
                          const float* __restrict__ K,
                          const float* __restrict__ E,
                          float* __restrict__ mats,
                          float* __restrict__ depth,
                          _Float16* __restrict__ featT) {
    int b = blockIdx.x;
    if (b < NB_SOFT) {
        int tid = b * 256 + threadIdx.x;
        if (tid < S_CAMS * 16) {
            int s = tid >> 4, ij = tid & 15;
            int i = ij >> 2, j = ij & 3;
            const float* Ks = K + s * 16;
            const float* Es = E + s * 16;
            float acc = 0.f;
            #pragma unroll
            for (int k = 0; k < 4; ++k) acc += Ks[i*4+k] * Es[k*4+j];
            mats[tid] = acc;
        }
        if (tid < S_CAMS * PIX) {
            int s = tid / PIX;
            int p = tid - s * PIX;
            const float* base = feat + s * CHW + p;   // ch 0..31 = depth logits
            float v[D_BINS];
            float m = -3.4e38f;
            #pragma unroll
            for (int d = 0; d < D_BINS; ++d) {
                v[d] = base[d * PIX];
                m = fmaxf(m, v[d]);
            }
            float sum = 0.f;
            #pragma unroll
            for (int d = 0; d < D_BINS; ++d) {
                v[d] = __expf(v[d] - m);
                sum += v[d];
            }
            float inv = 1.f / sum;
            float* dst = depth + s * (D_BINS * PIX) + p;   // [t][pix] strided
            #pragma unroll
            for (int d = 0; d < D_BINS; ++d) dst[d * PIX] = v[d] * inv;
        }
    } else {
        int t = (b - NB_SOFT) * 256 + threadIdx.x;   // < 4*12*3600 exactly
        int s  = t / (12 * PIX);
        int r  = t - s * (12 * PIX);
        int c8 = r / PIX;
        int p  = r - c8 * PIX;
        const float* src = feat + s * CHW + (D_BINS + c8 * 8) * PIX + p;
        h8 o;
        #pragma unroll
        for (int i = 0; i < 8; ++i) o[i] = (_Float16)src[i * PIX];
        ((h8*)featT)[(size_t)(s * PIX + p) * 12 + c8] = o;
    }
}

// Main (fast): 4 lanes per voxel (wave = 16 voxels x 4 subs).
// Weight phase distributed: sub-lane s computes camera s only, then width-4
// shuffles broadcast the 16 (w, off) pairs and butterfly-reduce one_sum.
// Clamps remapped to in-bounds 2x2x2 base + reassigned weights (== reference
// clamp+mask semantics). Feature phase: per corner, sub-lane loads its 16 B
// quarter of the pixel's 192 B channel row (full 64 B line per 4-lane group);
// per-camera PER-WAVE skip when no lane has nonzero weight for that camera.
__global__ __launch_bounds__(256, 4) void lift_fast(
    const _Float16* __restrict__ featT,
    const float* __restrict__ E,
    const float* __restrict__ mats,
    const float* __restrict__ depth,    // [s][32][PIX] f32
    float* __restrict__ out) {
    int t = blockIdx.x * 256 + threadIdx.x;
    int sub = t & 3;
    int vox = t >> 2;
    int xi = vox & (XD - 1);
    int zi = (vox >> 7) & (ZD - 1);
    int yi = vox >> 10;

    float xw = -25.f + (xi + 0.5f) * (50.f / XD);
    float yw = -25.f + (yi + 0.5f) * (50.f / YD);
    float zw = (zi + 0.5f) * 0.5f;

    // ---- weight phase: this lane handles camera s == sub ----
    float w4[4];
    int   off4[4];          // h8 index (without +sub)
    float one_s;
    {
        int s = sub;
        const float* P  = mats + s * 16;
        const float* Es = E + s * 16;
        float zcam = Es[8]*xw + Es[9]*yw + Es[10]*zw + Es[11];
        float px = P[0]*xw + P[1]*yw + P[2]*zw  + P[3];
        float py = P[4]*xw + P[5]*yw + P[6]*zw  + P[7];
        float pz = P[8]*xw + P[9]*yw + P[10]*zw + P[11];
        float zc = fmaxf(pz, 1e-6f);
        float xp = px / zc;
        float yp = py / zc;
        float zt = (float)(D_BINS - 1) * (zcam - 2.f) * (1.f / 30.f);
        float vmask = (xp > -0.5f && xp < (float)WFD - 0.5f &&
                       yp > -0.5f && yp < (float)HFD - 0.5f &&
                       zcam > 0.f) ? 1.f : 0.f;
        float us = xp * ((float)WFD / (WFD - 1)) - 0.5f;
        float vs = yp * ((float)HFD / (HFD - 1)) - 0.5f;
        float ts = zt * ((float)D_BINS / (D_BINS - 1)) - 0.5f;
        float u0f = floorf(us), v0f = floorf(vs), t0f = floorf(ts);
        float fu = us - u0f, fv = vs - v0f, ft = ts - t0f;
        int u0 = (int)u0f, v0 = (int)v0f, tz = (int)t0f;
        float uw0 = (u0 >= 0     && u0 < WFD)      ? (1.f - fu) : 0.f;
        float uw1 = (u0 + 1 >= 0 && u0 + 1 < WFD)  ? fu         : 0.f;
        float vw0 = (v0 >= 0     && v0 < HFD)      ? (1.f - fv) : 0.f;
        float vw1 = (v0 + 1 >= 0 && v0 + 1 < HFD)  ? fv         : 0.f;
        float tw0 = (tz >= 0     && tz < D_BINS)   ? (1.f - ft) : 0.f;
        float tw1 = (tz + 1 >= 0 && tz + 1 < D_BINS) ? ft       : 0.f;
        int bu = min(max(u0, 0), WFD - 2);
        int bv = min(max(v0, 0), HFD - 2);
        int bt = min(max(tz, 0), D_BINS - 2);
        float uwA = (u0 == bu) ? uw0 : ((u0 == bu - 1) ? uw1 : 0.f);
        float uwB = (u0 == bu) ? uw1 : ((u0 == bu + 1) ? uw0 : 0.f);
        float vwA = (v0 == bv) ? vw0 : ((v0 == bv - 1) ? vw1 : 0.f);
        float vwB = (v0 == bv) ? vw1 : ((v0 == bv + 1) ? vw0 : 0.f);
        float twA = (tz == bt) ? tw0 : ((tz == bt - 1) ? tw1 : 0.f);
        float twB = (tz == bt) ? tw1 : ((tz == bt + 1) ? tw0 : 0.f);
        int pb = bv * WFD + bu;
        const float* dp0 = depth + (s * D_BINS + bt) * PIX + pb;
        const float* dp1 = dp0 + PIX;
        float gAA = twA * dp0[0]       + twB * dp1[0];
        float gAB = twA * dp0[1]       + twB * dp1[1];
        float gBA = twA * dp0[WFD]     + twB * dp1[WFD];
        float gBB = twA * dp0[WFD + 1] + twB * dp1[WFD + 1];
        float wsum_hw = (vwA + vwB) * (uwA + uwB);
        one_s = fmaxf(vmask * (twA + twB) * wsum_hw, 1.f);
        float sc = vmask * one_s;
        w4[0] = sc * vwA * uwA * gAA;
        w4[1] = sc * vwA * uwB * gAB;
        w4[2] = sc * vwB * uwA * gBA;
        w4[3] = sc * vwB * uwB * gBB;
        int pixbase = s * PIX + pb;
        off4[0] = pixbase * 12;
        off4[1] = (pixbase + 1) * 12;
        off4[2] = (pixbase + WFD) * 12;
        off4[3] = (pixbase + WFD + 1) * 12;
    }

    // group reduction of one_sum (4 lanes per voxel)
    float one_sum = one_s;
    one_sum += __shfl_xor(one_sum, 1, 4);
    one_sum += __shfl_xor(one_sum, 2, 4);
    float inv = 1.f / (1e-6f + one_sum);
    #pragma unroll
    for (int c = 0; c < 4; ++c) w4[c] *= inv;

    // broadcast all 16 (w, off) pairs to every lane of the group
    float w[16];
    int   off[16];
    #pragma unroll
    for (int s2 = 0; s2 < 4; ++s2) {
        #pragma unroll
        for (int c = 0; c < 4; ++c) {
            w[s2*4+c]   = __shfl(w4[c], s2, 4);
            off[s2*4+c] = __shfl(off4[c], s2, 4) + sub;
        }
    }

    float acc[24];
    #pragma unroll
    for (int j = 0; j < 24; ++j) acc[j] = 0.f;

    const h8* fT = (const h8*)featT;
    #pragma unroll
    for (int s2 = 0; s2 < 4; ++s2) {
        // all weights are >= 0; camera contributes iff its 4-corner sum > 0.
        float cs = (w[s2*4+0] + w[s2*4+1]) + (w[s2*4+2] + w[s2*4+3]);
        if (__any(cs != 0.f)) {        // wave-uniform skip of invisible cameras
            #pragma unroll
            for (int k2 = 0; k2 < 4; ++k2) {
                int k = s2 * 4 + k2;
                float wk = w[k];
                #pragma unroll
                for (int j = 0; j < 3; ++j) {
                    h8 v = fT[off[k] + 4 * j];
                    #pragma unroll
                    for (int i = 0; i < 8; ++i)
                        acc[j*8+i] = fmaf(wk, (float)v[i], acc[j*8+i]);
                }
            }
        }
    }

    int outsp = yi * XD + xi;
    #pragma unroll
    for (int j = 0; j < 3; ++j) {
        #pragma unroll
        for (int i = 0; i < 8; ++i) {
            int c = j * 32 + sub * 8 + i;   // channel owned by this lane
            __builtin_nontemporal_store(acc[j*8+i],
                &out[(c * ZD + zi) * (YD * XD) + outsp]);
        }
    }
}

// ---------------- FALLBACK PATH (R1, proven, ~1.84 MB ws) ----------------
__global__ void prep_fb(const float* __restrict__ feat,
                        const float* __restrict__ K,
                        const float* __restrict__ E,
                        float* __restrict__ mats,
                        float* __restrict__ depth) {
    int tid = blockIdx.x * blockDim.x + threadIdx.x;
    if (tid < S_CAMS * 16) {
        int s = tid >> 4, ij = tid & 15;
        int i = ij >> 2, j = ij & 3;
        const float* Ks = K + s * 16;
        const float* Es = E + s * 16;
        float acc = 0.f;
        #pragma unroll
        for (int k = 0; k < 4; ++k) acc += Ks[i*4+k] * Es[k*4+j];
        mats[tid] = acc;
    }
    if (tid < S_CAMS * PIX) {
        int s = tid / PIX;
        int p = tid - s * PIX;
        const float* base = feat + s * CHW + p;
        float v[D_BINS];
        float m = -3.4e38f;
        #pragma unroll
        for (int d = 0; d < D_BINS; ++d) {
            v[d] = base[d * PIX];
            m = fmaxf(m, v[d]);
        }
        float sum = 0.f;
        #pragma unroll
        for (int d = 0; d < D_BINS; ++d) {
            v[d] = __expf(v[d] - m);
            sum += v[d];
        }
        float inv = 1.f / sum;
        float* dst = depth + s * (D_BINS * PIX) + p;
        #pragma unroll
        for (int d = 0; d < D_BINS; ++d) dst[d * PIX] = v[d] * inv;
    }
}

__global__ __launch_bounds__(256) void lift_fb(
    const float* __restrict__ feat,
    const float* __restrict__ E,
    const float* __restrict__ mats,
    const float* __restrict__ depth,
    float* __restrict__ out) {
    int tid = blockIdx.x * 256 + threadIdx.x;
    int xi = tid & (XD - 1);
    int zi = (tid >> 7) & (ZD - 1);
    int yi = tid >> 10;

    float xw = -25.f + (xi + 0.5f) * (50.f / XD);
    float yw = -25.f + (yi + 0.5f) * (50.f / YD);
    float zw = (zi + 0.5f) * 0.5f;

    float w[16];
    int   off[16];
    float one_sum = 0.f;

    #pragma unroll
    for (int s = 0; s < S_CAMS; ++s) {
        const float* P  = mats + s * 16;
        const float* Es = E + s * 16;
        float zcam = Es[8]*xw + Es[9]*yw + Es[10]*zw + Es[11];
        float px = P[0]*xw + P[1]*yw + P[2]*zw  + P[3];
        float py = P[4]*xw + P[5]*yw + P[6]*zw  + P[7];
        float pz = P[8]*xw + P[9]*yw + P[10]*zw + P[11];
        float zc = fmaxf(pz, 1e-6f);
        float xp = px / zc;
        float yp = py / zc;
        float zt = (float)(D_BINS - 1) * (zcam - 2.f) * (1.f / 30.f);
        float vmask = (xp > -0.5f && xp < (float)WFD - 0.5f &&
                       yp > -0.5f && yp < (float)HFD - 0.5f &&
                       zcam > 0.f) ? 1.f : 0.f;
        float us = xp * ((float)WFD / (WFD - 1)) - 0.5f;
        float vs = yp * ((float)HFD / (HFD - 1)) - 0.5f;
        float ts = zt * ((float)D_BINS / (D_BINS - 1)) - 0.5f;
        float u0f = floorf(us), v0f = floorf(vs), t0f = floorf(ts);
        float fu = us - u0f, fv = vs - v0f, ft = ts - t0f;
        int u0 = (int)u0f, v0 = (int)v0f, t0 = (int)t0f;
        int u1 = u0 + 1, v1 = v0 + 1, t1 = t0 + 1;
        float wu0 = 1.f - fu, wu1 = fu;
        float wv0 = 1.f - fv, wv1 = fv;
        float wz0 = (t0 >= 0 && t0 < D_BINS) ? (1.f - ft) : 0.f;
        float wz1 = (t1 >= 0 && t1 < D_BINS) ? ft : 0.f;
        float mu0 = (u0 >= 0 && u0 < WFD) ? 1.f : 0.f;
        float mu1 = (u1 >= 0 && u1 < WFD) ? 1.f : 0.f;
        float mv0 = (v0 >= 0 && v0 < HFD) ? 1.f : 0.f;
        float mv1 = (v1 >= 0 && v1 < HFD) ? 1.f : 0.f;
        int u0c = min(max(u0, 0), WFD - 1), u1c = min(max(u1, 0), WFD - 1);
        int v0c = min(max(v0, 0), HFD - 1), v1c = min(max(v1, 0), HFD - 1);
        int t0c = min(max(t0, 0), D_BINS - 1), t1c = min(max(t1, 0), D_BINS - 1);
        int p00 = v0c * WFD + u0c, p01 = v0c * WFD + u1c;
        int p10 = v1c * WFD + u0c, p11 = v1c * WFD + u1c;
        const float* dep0 = depth + s * (D_BINS * PIX) + t0c * PIX;
        const float* dep1 = depth + s * (D_BINS * PIX) + t1c * PIX;
        float g00 = wz0 * dep0[p00] + wz1 * dep1[p00];
        float g01 = wz0 * dep0[p01] + wz1 * dep1[p01];
        float g10 = wz0 * dep0[p10] + wz1 * dep1[p10];
        float g11 = wz0 * dep0[p11] + wz1 * dep1[p11];
        float m00 = mv0 * mu0, m01 = mv0 * mu1, m10 = mv1 * mu0, m11 = mv1 * mu1;
        float ws00 = wv0 * wu0 * m00, ws01 = wv0 * wu1 * m01;
        float ws10 = wv1 * wu0 * m10, ws11 = wv1 * wu1 * m11;
        float wsum_hw = ws00 + ws01 + ws10 + ws11;
        float one_s = fmaxf(vmask * (wz0 + wz1) * wsum_hw, 1.f);
        one_sum += one_s;
        float sc = vmask * one_s;
        w[s*4+0] = sc * ws00 * g00;
        w[s*4+1] = sc * ws01 * g01;
        w[s*4+2] = sc * ws10 * g10;
        w[s*4+3] = sc * ws11 * g11;
        int base = s * CHW;
        off[s*4+0] = base + p00;
        off[s*4+1] = base + p01;
        off[s*4+2] = base + p10;
        off[s*4+3] = base + p11;
    }

    float inv = 1.f / (1e-6f + one_sum);
    #pragma unroll
    for (int k = 0; k < 16; ++k) w[k] *= inv;

    int c0 = blockIdx.y * 24;
    int outsp = yi * XD + xi;
    for (int c = c0; c < c0 + 24; ++c) {
        const float* fp = feat + (D_BINS + c) * PIX;
        float acc = 0.f;
        #pragma unroll
        for (int k = 0; k < 16; ++k) acc = fmaf(w[k], fp[off[k]], acc);
        out[(c * ZD + zi) * (YD * XD) + outsp] = acc;
    }
}

extern "C" void kernel_launch(void* const* d_in, const int* in_sizes, int n_in,
                              void* d_out, int out_size, void* d_ws, size_t ws_size,
                              hipStream_t stream) {
    const float* feat = (const float*)d_in[0];   // (4,128,45,80) f32
    const float* K    = (const float*)d_in[1];   // (4,4,4) f32
    const float* E    = (const float*)d_in[2];   // (4,4,4) f32
    float* out  = (float*)d_out;                 // (1,768,128,128) f32

    const size_t n_depth = (size_t)S_CAMS * PIX * D_BINS;   // 460800 f32
    const size_t n_feat  = (size_t)S_CAMS * PIX * CFEAT;    // 1382400 fp16
    const size_t need_fast = (64 + n_depth) * sizeof(float) + n_feat * sizeof(_Float16);

    float* mats  = (float*)d_ws;
    float* depth = mats + 64;

    if (ws_size >= need_fast) {
        _Float16* featT = (_Float16*)(depth + n_depth);   // 64B-aligned
        prep_fast<<<dim3(NB_SOFT + NB_TR), dim3(256), 0, stream>>>(
            feat, K, E, mats, depth, featT);
        lift_fast<<<dim3(NPTS * 4 / 256), dim3(256), 0, stream>>>(
            featT, E, mats, depth, out);
    } else {
        // proven R1 path: depth in [s][t][pix] layout, gather from original feat
        prep_fb<<<dim3((S_CAMS * PIX + 255) / 256), dim3(256), 0, stream>>>(
            feat, K, E, mats, depth);
        lift_fb<<<dim3(NPTS / 256, 4), dim3(256), 0, stream>>>(
            feat, E, mats, depth, out);
    }
}

// Round 8
// 89.428 us; speedup vs baseline: 1.8886x; 1.0025x over previous
//
#include <hip/hip_runtime.h>

#define S_CAMS 4
#define D_BINS 32
#define CFEAT  96
#define HFD    45
#define WFD    80
#define PIX    (HFD*WFD)        // 3600
#define CHW    (128*PIX)        // per-camera input stride (128 channels)
#define YD     128
#define ZD     8
#define XD     128
#define NPTS   (YD*ZD*XD)       // 131072

#define NB_SOFT 57              // ceil(4*3600/256) softmax blocks
#define NB_TR   675             // 4*12*3600/256 fp16-transpose blocks

typedef _Float16 h8 __attribute__((ext_vector_type(8)));   // 16 B

// ---------------- FAST PATH (~4.6 MB ws) ----------------
// Fused prep: blocks [0,NB_SOFT): mats = K@E + per-pixel softmax over 32
// depth logits -> depth[s][t][pix] f32. blocks [NB_SOFT,..): transpose+cast
// feat -> featT[s][pix][96] fp16 (pixel base 192 B = 64B-aligned).
__global__ void prep_fast(const float* __restrict__ feat,
                          const float* __restrict__ K,
                          const float* __restrict__ E,
                          float* __restrict__ mats,
                          float* __restrict__ depth,
                          _Float16* __restrict__ featT) {
    int b = blockIdx.x;
    if (b < NB_SOFT) {
        int tid = b * 256 + threadIdx.x;
        if (tid < S_CAMS * 16) {
            int s = tid >> 4, ij = tid & 15;
            int i = ij >> 2, j = ij & 3;
            const float* Ks = K + s * 16;
            const float* Es = E + s * 16;
            float acc = 0.f;
            #pragma unroll
            for (int k = 0; k < 4; ++k) acc += Ks[i*4+k] * Es[k*4+j];
            mats[tid] = acc;
        }
        if (tid < S_CAMS * PIX) {
            int s = tid / PIX;
            int p = tid - s * PIX;
            const float* base = feat + s * CHW + p;   // ch 0..31 = depth logits
            float v[D_BINS];
            float m = -3.4e38f;
            #pragma unroll
            for (int d = 0; d < D_BINS; ++d) {
                v[d] = base[d * PIX];
                m = fmaxf(m, v[d]);
            }
            float sum = 0.f;
            #pragma unroll
            for (int d = 0; d < D_BINS; ++d) {
                v[d] = __expf(v[d] - m);
                sum += v[d];
            }
            float inv = 1.f / sum;
            float* dst = depth + s * (D_BINS * PIX) + p;   // [t][pix] strided
            #pragma unroll
            for (int d = 0; d < D_BINS; ++d) dst[d * PIX] = v[d] * inv;
        }
    } else {
        int t = (b - NB_SOFT) * 256 + threadIdx.x;   // < 4*12*3600 exactly
        int s  = t / (12 * PIX);
        int r  = t - s * (12 * PIX);
        int c8 = r / PIX;
        int p  = r - c8 * PIX;
        const float* src = feat + s * CHW + (D_BINS + c8 * 8) * PIX + p;
        h8 o;
        #pragma unroll
        for (int i = 0; i < 8; ++i) o[i] = (_Float16)src[i * PIX];
        ((h8*)featT)[(size_t)(s * PIX + p) * 12 + c8] = o;
    }
}

// Main (fast): 4 lanes per voxel (wave = 16 voxels x 4 subs).
// Weight phase distributed: sub-lane s computes camera s only, then width-4
// shuffles broadcast the 16 (w, off) pairs and butterfly-reduce one_sum.
// Clamps remapped to in-bounds 2x2x2 base + reassigned weights (== reference
// clamp+mask semantics). Feature phase: per corner, sub-lane loads its 16 B
// quarter of the pixel's 192 B channel row (full 64 B line per 4-lane group);
// GROUP-UNIFORM skip (cs is identical across the 4 lanes of a voxel): groups
// with zero camera weight are exec-masked off -> no line fetches, and
// s_cbranch_execz skips whole cameras nobody sees.
__global__ __launch_bounds__(256, 4) void lift_fast(
    const _Float16* __restrict__ featT,
    const float* __restrict__ E,
    const float* __restrict__ mats,
    const float* __restrict__ depth,    // [s][32][PIX] f32
    float* __restrict__ out) {
    int t = blockIdx.x * 256 + threadIdx.x;
    int sub = t & 3;
    int vox = t >> 2;
    int xi = vox & (XD - 1);
    int zi = (vox >> 7) & (ZD - 1);
    int yi = vox >> 10;

    float xw = -25.f + (xi + 0.5f) * (50.f / XD);
    float yw = -25.f + (yi + 0.5f) * (50.f / YD);
    float zw = (zi + 0.5f) * 0.5f;

    // ---- weight phase: this lane handles camera s == sub ----
    float w4[4];
    int   off4[4];          // h8 index (without +sub)
    float one_s;
    {
        int s = sub;
        const float* P  = mats + s * 16;
        const float* Es = E + s * 16;
        float zcam = Es[8]*xw + Es[9]*yw + Es[10]*zw + Es[11];
        float px = P[0]*xw + P[1]*yw + P[2]*zw  + P[3];
        float py = P[4]*xw + P[5]*yw + P[6]*zw  + P[7];
        float pz = P[8]*xw + P[9]*yw + P[10]*zw + P[11];
        float zc = fmaxf(pz, 1e-6f);
        float xp = px / zc;
        float yp = py / zc;
        float zt = (float)(D_BINS - 1) * (zcam - 2.f) * (1.f / 30.f);
        float vmask = (xp > -0.5f && xp < (float)WFD - 0.5f &&
                       yp > -0.5f && yp < (float)HFD - 0.5f &&
                       zcam > 0.f) ? 1.f : 0.f;
        float us = xp * ((float)WFD / (WFD - 1)) - 0.5f;
        float vs = yp * ((float)HFD / (HFD - 1)) - 0.5f;
        float ts = zt * ((float)D_BINS / (D_BINS - 1)) - 0.5f;
        float u0f = floorf(us), v0f = floorf(vs), t0f = floorf(ts);
        float fu = us - u0f, fv = vs - v0f, ft = ts - t0f;
        int u0 = (int)u0f, v0 = (int)v0f, tz = (int)t0f;
        float uw0 = (u0 >= 0     && u0 < WFD)      ? (1.f - fu) : 0.f;
        float uw1 = (u0 + 1 >= 0 && u0 + 1 < WFD)  ? fu         : 0.f;
        float vw0 = (v0 >= 0     && v0 < HFD)      ? (1.f - fv) : 0.f;
        float vw1 = (v0 + 1 >= 0 && v0 + 1 < HFD)  ? fv         : 0.f;
        float tw0 = (tz >= 0     && tz < D_BINS)   ? (1.f - ft) : 0.f;
        float tw1 = (tz + 1 >= 0 && tz + 1 < D_BINS) ? ft       : 0.f;
        int bu = min(max(u0, 0), WFD - 2);
        int bv = min(max(v0, 0), HFD - 2);
        int bt = min(max(tz, 0), D_BINS - 2);
        float uwA = (u0 == bu) ? uw0 : ((u0 == bu - 1) ? uw1 : 0.f);
        float uwB = (u0 == bu) ? uw1 : ((u0 == bu + 1) ? uw0 : 0.f);
        float vwA = (v0 == bv) ? vw0 : ((v0 == bv - 1) ? vw1 : 0.f);
        float vwB = (v0 == bv) ? vw1 : ((v0 == bv + 1) ? vw0 : 0.f);
        float twA = (tz == bt) ? tw0 : ((tz == bt - 1) ? tw1 : 0.f);
        float twB = (tz == bt) ? tw1 : ((tz == bt + 1) ? tw0 : 0.f);
        int pb = bv * WFD + bu;
        const float* dp0 = depth + (s * D_BINS + bt) * PIX + pb;
        const float* dp1 = dp0 + PIX;
        float2 dA0 = *(const float2*)dp0;          // {dp0[0], dp0[1]}
        float2 dA1 = *(const float2*)(dp0 + WFD);  // {dp0[80], dp0[81]}
        float2 dB0 = *(const float2*)dp1;
        float2 dB1 = *(const float2*)(dp1 + WFD);
        float gAA = twA * dA0.x + twB * dB0.x;
        float gAB = twA * dA0.y + twB * dB0.y;
        float gBA = twA * dA1.x + twB * dB1.x;
        float gBB = twA * dA1.y + twB * dB1.y;
        float wsum_hw = (vwA + vwB) * (uwA + uwB);
        one_s = fmaxf(vmask * (twA + twB) * wsum_hw, 1.f);
        float sc = vmask * one_s;
        w4[0] = sc * vwA * uwA * gAA;
        w4[1] = sc * vwA * uwB * gAB;
        w4[2] = sc * vwB * uwA * gBA;
        w4[3] = sc * vwB * uwB * gBB;
        int pixbase = s * PIX + pb;
        off4[0] = pixbase * 12;
        off4[1] = (pixbase + 1) * 12;
        off4[2] = (pixbase + WFD) * 12;
        off4[3] = (pixbase + WFD + 1) * 12;
    }

    // group reduction of one_sum (4 lanes per voxel)
    float one_sum = one_s;
    one_sum += __shfl_xor(one_sum, 1, 4);
    one_sum += __shfl_xor(one_sum, 2, 4);
    float inv = 1.f / (1e-6f + one_sum);
    #pragma unroll
    for (int c = 0; c < 4; ++c) w4[c] *= inv;

    // broadcast all 16 (w, off) pairs to every lane of the group
    float w[16];
    int   off[16];
    #pragma unroll
    for (int s2 = 0; s2 < 4; ++s2) {
        #pragma unroll
        for (int c = 0; c < 4; ++c) {
            w[s2*4+c]   = __shfl(w4[c], s2, 4);
            off[s2*4+c] = __shfl(off4[c], s2, 4) + sub;
        }
    }

    float acc[24];
    #pragma unroll
    for (int j = 0; j < 24; ++j) acc[j] = 0.f;

    const h8* fT = (const h8*)featT;
    #pragma unroll
    for (int s2 = 0; s2 < 4; ++s2) {
        // all weights >= 0; camera contributes iff its 4-corner sum > 0.
        // cs is identical across the 4 lanes of a voxel-group -> group-uniform
        // branch: invisible groups are exec-masked (no line fetches), and if
        // no group sees this camera the whole body is skipped (execz).
        float cs = (w[s2*4+0] + w[s2*4+1]) + (w[s2*4+2] + w[s2*4+3]);
        if (cs != 0.f) {
            #pragma unroll
            for (int k2 = 0; k2 < 4; ++k2) {
                int k = s2 * 4 + k2;
                float wk = w[k];
                #pragma unroll
                for (int j = 0; j < 3; ++j) {
                    h8 v = fT[off[k] + 4 * j];
                    #pragma unroll
                    for (int i = 0; i < 8; ++i)
                        acc[j*8+i] = fmaf(wk, (float)v[i], acc[j*8+i]);
                }
            }
        }
    }

    int outsp = yi * XD + xi;
    #pragma unroll
    for (int j = 0; j < 3; ++j) {
        #pragma unroll
        for (int i = 0; i < 8; ++i) {
            int c = j * 32 + sub * 8 + i;   // channel owned by this lane
            __builtin_nontemporal_store(acc[j*8+i],
                &out[(c * ZD + zi) * (YD * XD) + outsp]);
        }
    }
}

// ---------------- FALLBACK PATH (R1, proven, ~1.84 MB ws) ----------------
__global__ void prep_fb(const float* __restrict__ feat,
                        const float* __restrict__ K,
                        const float* __restrict__ E,
                        float* __restrict__ mats,
                        float* __restrict__ depth) {
    int tid = blockIdx.x * blockDim.x + threadIdx.x;
    if (tid < S_CAMS * 16) {
        int s = tid >> 4, ij = tid & 15;
        int i = ij >> 2, j = ij & 3;
        const float* Ks = K + s * 16;
        const float* Es = E + s * 16;
        float acc = 0.f;
        #pragma unroll
        for (int k = 0; k < 4; ++k) acc += Ks[i*4+k] * Es[k*4+j];
        mats[tid] = acc;
    }
    if (tid < S_CAMS * PIX) {
        int s = tid / PIX;
        int p = tid - s * PIX;
        const float* base = feat + s * CHW + p;
        float v[D_BINS];
        float m = -3.4e38f;
        #pragma unroll
        for (int d = 0; d < D_BINS; ++d) {
            v[d] = base[d * PIX];
            m = fmaxf(m, v[d]);
        }
        float sum = 0.f;
        #pragma unroll
        for (int d = 0; d < D_BINS; ++d) {
            v[d] = __expf(v[d] - m);
            sum += v[d];
        }
        float inv = 1.f / sum;
        float* dst = depth + s * (D_BINS * PIX) + p;
        #pragma unroll
        for (int d = 0; d < D_BINS; ++d) dst[d * PIX] = v[d] * inv;
    }
}

__global__ __launch_bounds__(256) void lift_fb(
    const float* __restrict__ feat,
    const float* __restrict__ E,
    const float* __restrict__ mats,
    const float* __restrict__ depth,
    float* __restrict__ out) {
    int tid = blockIdx.x * 256 + threadIdx.x;
    int xi = tid & (XD - 1);
    int zi = (tid >> 7) & (ZD - 1);
    int yi = tid >> 10;

    float xw = -25.f + (xi + 0.5f) * (50.f / XD);
    float yw = -25.f + (yi + 0.5f) * (50.f / YD);
    float zw = (zi + 0.5f) * 0.5f;

    float w[16];
    int   off[16];
    float one_sum = 0.f;

    #pragma unroll
    for (int s = 0; s < S_CAMS; ++s) {
        const float* P  = mats + s * 16;
        const float* Es = E + s * 16;
        float zcam = Es[8]*xw + Es[9]*yw + Es[10]*zw + Es[11];
        float px = P[0]*xw + P[1]*yw + P[2]*zw  + P[3];
        float py = P[4]*xw + P[5]*yw + P[6]*zw  + P[7];
        float pz = P[8]*xw + P[9]*yw + P[10]*zw + P[11];
        float zc = fmaxf(pz, 1e-6f);
        float xp = px / zc;
        float yp = py / zc;
        float zt = (float)(D_BINS - 1) * (zcam - 2.f) * (1.f / 30.f);
        float vmask = (xp > -0.5f && xp < (float)WFD - 0.5f &&
                       yp > -0.5f && yp < (float)HFD - 0.5f &&
                       zcam > 0.f) ? 1.f : 0.f;
        float us = xp * ((float)WFD / (WFD - 1)) - 0.5f;
        float vs = yp * ((float)HFD / (HFD - 1)) - 0.5f;
        float ts = zt * ((float)D_BINS / (D_BINS - 1)) - 0.5f;
        float u0f = floorf(us), v0f = floorf(vs), t0f = floorf(ts);
        float fu = us - u0f, fv = vs - v0f, ft = ts - t0f;
        int u0 = (int)u0f, v0 = (int)v0f, t0 = (int)t0f;
        int u1 = u0 + 1, v1 = v0 + 1, t1 = t0 + 1;
        float wu0 = 1.f - fu, wu1 = fu;
        float wv0 = 1.f - fv, wv1 = fv;
        float wz0 = (t0 >= 0 && t0 < D_BINS) ? (1.f - ft) : 0.f;
        float wz1 = (t1 >= 0 && t1 < D_BINS) ? ft : 0.f;
        float mu0 = (u0 >= 0 && u0 < WFD) ? 1.f : 0.f;
        float mu1 = (u1 >= 0 && u1 < WFD) ? 1.f : 0.f;
        float mv0 = (v0 >= 0 && v0 < HFD) ? 1.f : 0.f;
        float mv1 = (v1 >= 0 && v1 < HFD) ? 1.f : 0.f;
        int u0c = min(max(u0, 0), WFD - 1), u1c = min(max(u1, 0), WFD - 1);
        int v0c = min(max(v0, 0), HFD - 1), v1c = min(max(v1, 0), HFD - 1);
        int t0c = min(max(t0, 0), D_BINS - 1), t1c = min(max(t1, 0), D_BINS - 1);
        int p00 = v0c * WFD + u0c, p01 = v0c * WFD + u1c;
        int p10 = v1c * WFD + u0c, p11 = v1c * WFD + u1c;
        const float* dep0 = depth + s * (D_BINS * PIX) + t0c * PIX;
        const float* dep1 = depth + s * (D_BINS * PIX) + t1c * PIX;
        float g00 = wz0 * dep0[p00] + wz1 * dep1[p00];
        float g01 = wz0 * dep0[p01] + wz1 * dep1[p01];
        float g10 = wz0 * dep0[p10] + wz1 * dep1[p10];
        float g11 = wz0 * dep0[p11] + wz1 * dep1[p11];
        float m00 = mv0 * mu0, m01 = mv0 * mu1, m10 = mv1 * mu0, m11 = mv1 * mu1;
        float ws00 = wv0 * wu0 * m00, ws01 = wv0 * wu1 * m01;
        float ws10 = wv1 * wu0 * m10, ws11 = wv1 * wu1 * m11;
        float wsum_hw = ws00 + ws01 + ws10 + ws11;
        float one_s = fmaxf(vmask * (wz0 + wz1) * wsum_hw, 1.f);
        one_sum += one_s;
        float sc = vmask * one_s;
        w[s*4+0] = sc * ws00 * g00;
        w[s*4+1] = sc * ws01 * g01;
        w[s*4+2] = sc * ws10 * g10;
        w[s*4+3] = sc * ws11 * g11;
        int base = s * CHW;
        off[s*4+0] = base + p00;
        off[s*4+1] = base + p01;
        off[s*4+2] = base + p10;
        off[s*4+3] = base + p11;
    }

    float inv = 1.f / (1e-6f + one_sum);
    #pragma unroll
    for (int k = 0; k < 16; ++k) w[k] *= inv;

    int c0 = blockIdx.y * 24;
    int outsp = yi * XD + xi;
    for (int c = c0; c < c0 + 24; ++c) {
        const float* fp = feat + (D_BINS + c) * PIX;
        float acc = 0.f;
        #pragma unroll
        for (int k = 0; k < 16; ++k) acc = fmaf(w[k], fp[off[k]], acc);
        out[(c * ZD + zi) * (YD * XD) + outsp] = acc;
    }
}

extern "C" void kernel_launch(void* const* d_in, const int* in_sizes, int n_in,
                              void* d_out, int out_size, void* d_ws, size_t ws_size,
                              hipStream_t stream) {
    const float* feat = (const float*)d_in[0];   // (4,128,45,80) f32
    const float* K    = (const float*)d_in[1];   // (4,4,4) f32
    const float* E    = (const float*)d_in[2];   // (4,4,4) f32
    float* out  = (float*)d_out;                 // (1,768,128,128) f32

    const size_t n_depth = (size_t)S_CAMS * PIX * D_BINS;   // 460800 f32
    const size_t n_feat  = (size_t)S_CAMS * PIX * CFEAT;    // 1382400 fp16
    const size_t need_fast = (64 + n_depth) * sizeof(float) + n_feat * sizeof(_Float16);

    float* mats  = (float*)d_ws;
    float* depth = mats + 64;

    if (ws_size >= need_fast) {
        _Float16* featT = (_Float16*)(depth + n_depth);   // 64B-aligned
        prep_fast<<<dim3(NB_SOFT + NB_TR), dim3(256), 0, stream>>>(
            feat, K, E, mats, depth, featT);
        lift_fast<<<dim3(NPTS * 4 / 256), dim3(256), 0, stream>>>(
            featT, E, mats, depth, out);
    } else {
        // proven R1 path: depth in [s][t][pix] layout, gather from original feat
        prep_fb<<<dim3((S_CAMS * PIX + 255) / 256), dim3(256), 0, stream>>>(
            feat, K, E, mats, depth);
        lift_fb<<<dim3(NPTS / 256, 4), dim3(256), 0, stream>>>(
            feat, E, mats, depth, out);
    }
}